// Round 9
// baseline (563.039 us; speedup 1.0000x reference)
//
#include <hip/hip_runtime.h>
#include <hip/hip_bf16.h>
#include <cmath>

#define BB 4
#define LL 2304
#define CC 768
#define DSTATE 16
#define DINNER 768
#define DTRANK 48
#define MTOK (BB*LL)          // 9216
#define NCH 48
#define LCH (LL/NCH)          // 48

// per-direction strides (element units)
#define S_XZ   14155776L
#define S_XC   7077888L
#define S_DT   7077888L
#define S_BC   294912L
#define S_YB   7077888L
#define S_AP   2359296L
#define S_XCR  79036416L      // gap between xcR dir0 (xn slot) and dir1 (h1 slot)

#define L2E 1.4426950408889634f

typedef __bf16 bf16_t;
typedef __bf16 bf16x8 __attribute__((ext_vector_type(8)));
typedef float  f32x4  __attribute__((ext_vector_type(4)));

__device__ __forceinline__ float silu_f(float v){ return v / (1.0f + __expf(-v)); }
__device__ __forceinline__ float softplus_f(float v){
    return fmaxf(v,0.f) + __logf(1.0f + __expf(-fabsf(v)));
}

typedef __attribute__((address_space(3))) void  lds_vt;
typedef __attribute__((address_space(1))) void  gbl_vt;
__device__ __forceinline__ void async_copy16(const void* g, void* l){
    __builtin_amdgcn_global_load_lds((const gbl_vt*)g, (lds_vt*)l, 16, 0, 0);
}

// TILED time-contiguous layout for scan operands:
//   X[tb][Ndim][8], element (r,n) at ((r>>3)*Ndim + n)*8 + (r&7).

// ---------------- weight fp32 -> bf16 conversion ----------------------------
__global__ __launch_bounds__(256)
void wconv_k(const float* __restrict__ a0, const float* __restrict__ a1,
             const float* __restrict__ a2, const float* __restrict__ a3,
             const float* __restrict__ a4, const float* __restrict__ a5,
             bf16_t* __restrict__ dst)
{
    const int cum[7]  = {0,1179648,2359296,3538944,4128768,4153344,4177920};
    const int dofs[6] = {0,1179648,2359296,3538944,4718592,5332992};
    const float* srcs[6] = {a0,a1,a2,a3,a4,a5};
    int idx = blockIdx.x*256 + threadIdx.x;
    if (idx >= 4177920) return;
    int seg = 0;
    while (idx >= cum[seg+1]) ++seg;
    dst[dofs[seg] + idx - cum[seg]] = (bf16_t)srcs[seg][idx - cum[seg]];
}

// ---------------- transpose+convert 768x768 fp32 -> bf16 (dst = src^T) ------
__global__ __launch_bounds__(256)
void transp_k(const float* __restrict__ s0, const float* __restrict__ s1,
              bf16_t* __restrict__ d0, bf16_t* __restrict__ d1)
{
    __shared__ float tile[32][33];
    const float* src = blockIdx.z ? s1 : s0;
    bf16_t* dst = blockIdx.z ? d1 : d0;
    int c0 = blockIdx.y*32, d0c = blockIdx.x*32;
    int tx = threadIdx.x & 31, ty = threadIdx.x >> 5;   // ty 0..7
#pragma unroll
    for (int r=0;r<4;++r)
        tile[ty+8*r][tx] = src[(long)(c0+ty+8*r)*768 + d0c+tx];
    __syncthreads();
#pragma unroll
    for (int r=0;r<4;++r)
        dst[(long)(d0c+ty+8*r)*768 + c0+tx] = (bf16_t)tile[tx][ty+8*r];
}

// ---------------- inverse permutations ---------------------------------------
__global__ __launch_bounds__(256)
void inv_k(const int* __restrict__ sidx, int* __restrict__ rf, int* __restrict__ rb)
{
    int t = blockIdx.x*256 + threadIdx.x;
    if (t >= LL) return;
    rf[sidx[t]] = t;
    rb[sidx[LL-1-t]] = t;
}

// ---------------- combo weight: dst[n*768+k] = sum_r dtw[n*48+r]*xproj[r*768+k]
__global__ __launch_bounds__(256)
void combo_k(const float* __restrict__ dtw, const float* __restrict__ xproj,
             bf16_t* __restrict__ dst)
{
    __shared__ float row[48];
    int n = blockIdx.x;
    if (threadIdx.x < 48) row[threadIdx.x] = dtw[n*48 + threadIdx.x];
    __syncthreads();
#pragma unroll
    for (int kk=0; kk<3; ++kk){
        int k = threadIdx.x + 256*kk;
        float s = 0.f;
#pragma unroll 8
        for (int r=0; r<48; ++r) s += row[r]*xproj[r*768 + k];
        dst[n*768 + k] = (bf16_t)s;
    }
}

// ---------------- LayerNorm (per token, C=768) -> bf16 ----------------------
__global__ __launch_bounds__(256)
void ln_k(const float* __restrict__ x, const float* __restrict__ g,
          const float* __restrict__ bta, bf16_t* __restrict__ xn)
{
    int row = blockIdx.x;
    const float* xr = x + (long)row*CC;
    int tid = threadIdx.x;
    float v[3];
#pragma unroll
    for (int r=0;r<3;++r) v[r] = xr[tid + 256*r];
    float s  = v[0]+v[1]+v[2];
    float s2 = v[0]*v[0]+v[1]*v[1]+v[2]*v[2];
    __shared__ float red[8];
    for (int o=32;o;o>>=1){ s += __shfl_down(s,o); s2 += __shfl_down(s2,o); }
    int wv = tid>>6, ln = tid&63;
    if (ln==0){ red[wv]=s; red[4+wv]=s2; }
    __syncthreads();
    if (tid==0){
        red[0] = red[0]+red[1]+red[2]+red[3];
        red[4] = red[4]+red[5]+red[6]+red[7];
    }
    __syncthreads();
    float mu  = red[0]*(1.0f/CC);
    float var = red[4]*(1.0f/CC) - mu*mu;
    float rstd = rsqrtf(var + 1e-6f);
#pragma unroll
    for (int r=0;r<3;++r){
        int c = tid + 256*r;
        xn[(long)row*CC + c] = (bf16_t)((v[r]-mu)*rstd*g[c] + bta[c]);
    }
}

// ---------------- depthwise causal conv (k=4) + silu, tiled layout ----------
__global__ __launch_bounds__(256)
void conv_k(const bf16_t* __restrict__ xzT, const float* __restrict__ cw0,
            const float* __restrict__ cw1, const float* __restrict__ cb0,
            const float* __restrict__ cb1, bf16_t* __restrict__ xcT,
            bf16_t* __restrict__ xcR0, bf16_t* __restrict__ xcR1)
{
    const int dir = blockIdx.y;
    const bf16_t* src = xzT + (long)dir*S_XZ;
    bf16_t* dstT = xcT + (long)dir*S_XC;
    bf16_t* dstR = dir ? xcR1 : xcR0;
    const float* cw = dir ? cw1 : cw0;
    const float* cb = dir ? cb1 : cb0;
    int idx = blockIdx.x*256 + threadIdx.x;     // 768 * 576
    int d = idx % 768;                          // consecutive lanes -> consecutive d
    int chunk = idx / 768;                      // 0..575  (16-t chunks)
    int tb = chunk*2;
    int r0 = chunk*16;

    bf16x8 c0 = *(const bf16x8*)&src[((long)tb*1536 + d)*8];
    bf16x8 c1 = *(const bf16x8*)&src[((long)(tb+1)*1536 + d)*8];
    float xm3, xm2, xm1;
    if (r0 % LL){
        bf16x8 pv = *(const bf16x8*)&src[((long)(tb-1)*1536 + d)*8];
        xm3=(float)pv[5]; xm2=(float)pv[6]; xm1=(float)pv[7];
    } else { xm3=0.f; xm2=0.f; xm1=0.f; }

    float4 w = *(const float4*)&cw[d*4];
    float bz = cb[d];

    float xx[16];
#pragma unroll
    for (int u=0;u<8;++u){ xx[u]=(float)c0[u]; xx[8+u]=(float)c1[u]; }
    bf16x8 o0, o1;
#pragma unroll
    for (int u=0;u<16;++u){
        float cur = xx[u];
        float acc = bz + w.x*xm3 + w.y*xm2 + w.z*xm1 + w.w*cur;
        float r = silu_f(acc);
        if (u < 8) o0[u] = (bf16_t)r; else o1[u-8] = (bf16_t)r;
        xm3 = xm2; xm2 = xm1; xm1 = cur;
    }
    *(bf16x8*)&dstT[((long)tb*768 + d)*8]     = o0;
    *(bf16x8*)&dstT[((long)(tb+1)*768 + d)*8] = o1;
#pragma unroll
    for (int u=0;u<8;++u){
        dstR[(long)(r0+u)*DINNER + d]   = o0[u];
        dstR[(long)(r0+8+u)*DINNER + d] = o1[u];
    }
}

// ---------------- GEMM4: LDS-staged MFMA GEMM, 128x128 tile, BK=64 ----------
// EPI: 2 store bf16 (staged wide) | 3 gelu+bias->bf16 (staged) |
//      4 bias+resid->f32 STAGED float4 | 5 softplus staged + bc scalar |
//      6 bf16 TRANSPOSED-TILED (staged) | 7 softplus TRANSPOSED-TILED + bc
// R9: Cs epilogue XOR-swizzle (col ^ ((row>>2)&3)<<4) kills the 8-lane/bank
// write conflicts (SQ_LDS_BANK_CONFLICT 884K/dispatch); EPI4 staged f32 with
// coalesced float4 resid+store (was 64 scalar stores + 64 scalar loads/thr).
template<int GATHER, int SCATTER, int EPI>
__global__ __launch_bounds__(256)
void gemm4_k(const bf16_t* __restrict__ A, long a_stride, int lda,
             const bf16_t* __restrict__ W0, const bf16_t* __restrict__ W1,
             int N, int K,
             void* __restrict__ out1, long o1_stride,
             void* __restrict__ out2, long o2_stride,
             int ldc, int ccol_stride,
             const float* __restrict__ bias0, const float* __restrict__ bias1,
             const float* __restrict__ resid,
             const int* __restrict__ sidx,
             const int* __restrict__ ridx0, const int* __restrict__ ridx1)
{
    __shared__ __align__(16) bf16_t smem[2*128*64];   // As | Bs ; reused as Cs
    bf16_t* As = smem;
    bf16_t* Bs = smem + 128*64;

    const int tid  = threadIdx.x;
    const int lane = tid & 63;
    const int w    = tid >> 6;
    const int ln16 = lane & 15;
    const int q    = lane >> 4;
    const int dir  = blockIdx.z;

    const bf16_t* Ad = A + (long)dir*a_stride;
    const bf16_t* W  = dir ? W1 : W0;
    const float* bias = dir ? bias1 : bias0;

    const int m0 = blockIdx.x*128;
    const int n0 = blockIdx.y*128;

    const int srow = lane >> 3;
    const int csrc = (lane & 7) ^ srow;
    const bf16_t* gA[4]; const bf16_t* gA1[4]; const bf16_t* gB[4];
#pragma unroll
    for (int inst=0; inst<4; ++inst){
        int row = w*32 + inst*8 + srow;
        int r = m0 + row;
        if (GATHER == 4){
            int t = r % LL; int bo = r - t;
            gA[inst]  = A + (long)(bo + ridx0[t])*lda + csrc*8;
            gA1[inst] = A + a_stride + (long)(bo + ridx1[t])*lda + csrc*8;
        } else {
            int sr = r;
            if (GATHER == 3){
                int t = r % LL; int bo = r - t;
                sr = bo + (dir ? sidx[LL-1-t] : sidx[t]);
            }
            gA[inst] = Ad + (long)sr*lda + csrc*8;
        }
        int n = n0 + row; if (n >= N) n = N-1;
        gB[inst] = W + (long)n*K + csrc*8;
    }

    f32x4 acc[4][4];
#pragma unroll
    for (int i=0;i<4;++i)
#pragma unroll
      for (int j=0;j<4;++j) acc[i][j] = (f32x4){0.f,0.f,0.f,0.f};

    const int e = ln16 & 7;
    const int ar_base = ((w>>1)*64 + ln16)*64;
    const int br_base = ((w&1)*64 + ln16)*64;

    for (int k0 = 0; k0 < K; k0 += 64){
#pragma unroll
        for (int inst=0; inst<4; ++inst){
            bf16_t* la = As + (w*256 + inst*64)*8;
            bf16_t* lb = Bs + (w*256 + inst*64)*8;
            const bf16_t* asrc;
            if (GATHER == 4)
                asrc = (k0 >= 768) ? (gA1[inst] + (k0 - 768)) : (gA[inst] + k0);
            else
                asrc = gA[inst] + k0;
            async_copy16(asrc, la);
            async_copy16(gB[inst] + k0, lb);
        }
        __syncthreads();
#pragma unroll
        for (int kk=0; kk<2; ++kk){
            const int ce = (((kk<<2)|q) ^ e)*8;
            bf16x8 af[4], bf[4];
#pragma unroll
            for (int i=0;i<4;++i) af[i] = *(const bf16x8*)&As[ar_base + i*16*64 + ce];
#pragma unroll
            for (int j=0;j<4;++j) bf[j] = *(const bf16x8*)&Bs[br_base + j*16*64 + ce];
#pragma unroll
            for (int i=0;i<4;++i)
#pragma unroll
              for (int j=0;j<4;++j)
                acc[i][j] = __builtin_amdgcn_mfma_f32_16x16x32_bf16(af[i], bf[j], acc[i][j], 0,0,0);
        }
        __syncthreads();
    }

    const int mw = (w>>1)*64;
    const int nw = (w&1)*64;
    const int ccolb = ccol_stride*dir;

    const bool staged = (EPI==2) || (EPI==3) || (EPI==6) ||
                        ((EPI==5 || EPI==7) && n0 < 768);
    if (staged){
        bf16_t* Cs = smem;
#pragma unroll
        for (int i=0;i<4;++i){
#pragma unroll
            for (int reg=0; reg<4; ++reg){
                int rowl = mw + i*16 + q*4 + reg;
                int sw = ((rowl>>2)&3) << 4;      // bank swizzle (bits 4,5)
#pragma unroll
                for (int j=0;j<4;++j){
                    int coll = nw + j*16 + ln16;
                    float v = acc[i][j][reg];
                    if (EPI==3){
                        v += bias[n0 + coll];
                        v = 0.5f*v*(1.0f + erff(v*0.70710678118654752f));
                    } else if (EPI==5 || EPI==7){
                        v = softplus_f(v + bias[n0 + coll]);
                    }
                    Cs[rowl*128 + (coll ^ sw)] = (bf16_t)v;
                }
            }
        }
        __syncthreads();
        bf16_t* o = (bf16_t*)out1 + (long)dir*o1_stride;
        if (EPI==6 || EPI==7){
            // transposed-tiled store: X[((r>>3)*ldc + n)*8 + (r&7)]
#pragma unroll
            for (int c=0;c<8;++c){
                int chunk = tid + 256*c;        // 0..2047
                int nb  = chunk & 127;          // lane-consecutive n
                int tbl = chunk >> 7;           // 0..15 t-block within tile
                bf16x8 v;
#pragma unroll
                for (int u=0;u<8;++u){
                    int row = tbl*8 + u;
                    int sw = ((row>>2)&3) << 4;
                    v[u] = Cs[row*128 + (nb ^ sw)];
                }
                long base = ((long)(m0/8 + tbl)*ldc + (n0 + nb))*8;
                *(bf16x8*)&o[base] = v;
            }
        } else {
#pragma unroll
            for (int c=0;c<8;++c){
                int chunk = tid + 256*c;        // 0..2047
                int rowl = chunk >> 4;
                int cb   = chunk & 15;
                int swb  = (rowl>>2)&3;
                int r = m0 + rowl;
                int orow = r;
                if (SCATTER == 3){
                    int t = r % LL; int bo = r - t;
                    orow = bo + (dir ? sidx[LL-1-t] : sidx[t]);
                }
                *(int4*)&o[(long)orow*ldc + ccolb + n0 + cb*8] =
                    *(const int4*)&Cs[rowl*128 + ((cb ^ (swb<<1))*8)];
            }
        }
    } else if (EPI==4){
        // ---- staged f32 epilogue (two 64x128 halves), float4 resid+store ---
        float* Csf = (float*)smem;              // 64 x 128 f32 = 32KB
        float* o1 = (float*)out1;
#pragma unroll
        for (int hh=0; hh<2; ++hh){
            if ((w>>1) == hh){
#pragma unroll
                for (int i=0;i<4;++i){
#pragma unroll
                    for (int reg=0; reg<4; ++reg){
                        int rowl = i*16 + q*4 + reg;          // 0..63 in half
                        int sw = ((rowl>>2)&1) << 4;          // f32 swizzle
#pragma unroll
                        for (int j=0;j<4;++j){
                            int coll = nw + j*16 + ln16;
                            Csf[rowl*128 + (coll ^ sw)] =
                                acc[i][j][reg] + bias[n0 + coll];
                        }
                    }
                }
            }
            __syncthreads();
#pragma unroll
            for (int c=0;c<8;++c){
                int chunk = tid + 256*c;        // 0..2047
                int rowl = chunk >> 5;          // 0..63
                int c4   = chunk & 31;          // float4 block
                int sw4  = ((rowl>>2)&1) << 2;
                int r = m0 + hh*64 + rowl;
                int col = n0 + c4*4;
                float4 v = *(const float4*)&Csf[rowl*128 + ((c4 ^ sw4)<<2)];
                float4 rs = *(const float4*)&resid[(long)r*CC + col];
                v.x += rs.x; v.y += rs.y; v.z += rs.z; v.w += rs.w;
                *(float4*)&o1[(long)r*ldc + col] = v;
            }
            __syncthreads();
        }
    } else {
        // ---- scalar epilogue (EPI 5/7 bc-tile) ----
#pragma unroll
        for (int i=0;i<4;++i){
#pragma unroll
            for (int reg=0; reg<4; ++reg){
                int r = m0 + mw + i*16 + q*4 + reg;
#pragma unroll
                for (int j=0;j<4;++j){
                    int col = n0 + nw + j*16 + ln16;
                    if (col >= N) continue;
                    float v = acc[i][j][reg];
                    ((float*)out2 + (long)dir*o2_stride)[(long)r*32 + (col-768)] = v;
                }
            }
        }
    }
}

// ---------------- selective scan v7: tiled b128 loads, register-light -------
template<int PASS>
__global__ __launch_bounds__(256)
void scanp_k(const bf16_t* __restrict__ dtp, const bf16_t* __restrict__ xcp,
             const float* __restrict__ bcp, const bf16_t* __restrict__ xzp,
             const float* __restrict__ Al0, const float* __restrict__ Al1,
             const float* __restrict__ Dp0, const float* __restrict__ Dp1,
             float* __restrict__ Aprod, float* __restrict__ Hend,
             bf16_t* __restrict__ yout)
{
    __shared__ __align__(16) float s_bc[LCH*32];   // 6144 B

    const int dir = blockIdx.y;
    int blk = blockIdx.x;
    const int dblk = blk % 3; int tmp = blk / 3;
    const int j = tmp % NCH; const int b = tmp / NCH;
    const int tid = threadIdx.x;
    const long tbase = (long)b*LL + (long)j*LCH;
    const long tb0 = tbase >> 3;
    const int d = dblk*256 + tid;

    const float* gbc = bcp + dir*S_BC + tbase*32;
    async_copy16(gbc + tid*4, s_bc + tid*4);
    if (tid < 128) async_copy16(gbc + (256+tid)*4, s_bc + (256+tid)*4);

    const float* Al = dir ? Al1 : Al0;
    float ac2[16]; bool fast = true;
#pragma unroll
    for (int k=0;k<16;++k){
        float a = -__expf(Al[d*DSTATE + k]);
        fast = fast && (fabsf(a + (float)(k+1)) < 1e-3f*(float)(k+1));
        ac2[k] = a * L2E;
    }

    const bf16_t* gdt = dtp + dir*S_DT + (tb0*768  + d)*8;
    const bf16_t* gxc = xcp + dir*S_XC + (tb0*768  + d)*8;
    const bf16_t* gz  = xzp + dir*S_XZ + (tb0*1536 + 768 + d)*8;
    bf16_t* gy = yout + dir*S_YB + tbase*DINNER + d;

    const long o = dir*S_AP + ((long)(b*NCH + j)*DINNER + d)*DSTATE;

    float h[16];
    float dpv = 0.f;
    if (PASS==3){
#pragma unroll
        for (int g=0; g<4; ++g){
            f32x4 hv = *(const f32x4*)&Aprod[o + 4*g];
#pragma unroll
            for (int k=0;k<4;++k) h[g*4+k] = hv[k];
        }
        dpv = (dir ? Dp1 : Dp0)[d];
    } else {
#pragma unroll
        for (int k=0;k<16;++k) h[k] = 0.f;
    }
    float sdt = 0.f;

    __syncthreads();   // s_bc ready

#pragma unroll 1
    for (int cc=0; cc<LCH/8; ++cc){
        bf16x8 vdt = *(const bf16x8*)&gdt[(long)cc*6144];      // 768*8
        bf16x8 vxc = *(const bf16x8*)&gxc[(long)cc*6144];
        bf16x8 vz;
        if (PASS==3) vz = *(const bf16x8*)&gz[(long)cc*12288]; // 1536*8
#pragma unroll
        for (int u=0; u<8; ++u){
            const int t = cc*8 + u;
            float dt = (float)vdt[u];
            float xv = (float)vxc[u];
            float c = dt*xv;
            if (PASS==1) sdt += dt;
            const float* bcr = &s_bc[t*32];
            float p = 0.f;
            if (fast){
                float e1 = __builtin_amdgcn_exp2f(-L2E*dt);
                float e2 = e1*e1, e3 = e2*e1, e4 = e2*e2;
                float m = 1.0f;
#pragma unroll
                for (int g=0; g<4; ++g){
                    f32x4 Bv = *(const f32x4*)&bcr[g*4];
                    h[g*4+0] = (m*e1)*h[g*4+0] + c*Bv[0];
                    h[g*4+1] = (m*e2)*h[g*4+1] + c*Bv[1];
                    h[g*4+2] = (m*e3)*h[g*4+2] + c*Bv[2];
                    h[g*4+3] = (m*e4)*h[g*4+3] + c*Bv[3];
                    if (PASS==3){
                        f32x4 Cv = *(const f32x4*)&bcr[16 + g*4];
                        p += h[g*4+0]*Cv[0] + h[g*4+1]*Cv[1]
                           + h[g*4+2]*Cv[2] + h[g*4+3]*Cv[3];
                    }
                    m *= e4;
                }
            } else {
#pragma unroll
                for (int g=0; g<4; ++g){
                    f32x4 Bv = *(const f32x4*)&bcr[g*4];
#pragma unroll
                    for (int k=0;k<4;++k)
                        h[g*4+k] = __builtin_amdgcn_exp2f(dt*ac2[g*4+k])*h[g*4+k] + c*Bv[k];
                    if (PASS==3){
                        f32x4 Cv = *(const f32x4*)&bcr[16 + g*4];
                        p += h[g*4+0]*Cv[0] + h[g*4+1]*Cv[1]
                           + h[g*4+2]*Cv[2] + h[g*4+3]*Cv[3];
                    }
                }
            }
            if (PASS==3){
                float zv = (float)vz[u];
                gy[(long)t*DINNER] = (bf16_t)((p + dpv*xv) * silu_f(zv));
            }
        }
    }

    if (PASS==1){
        float e1s = __builtin_amdgcn_exp2f(-L2E*sdt);
        float e2s = e1s*e1s, e3s = e2s*e1s, e4s = e2s*e2s;
        float m = 1.0f;
#pragma unroll
        for (int g=0; g<4; ++g){
            f32x4 av, hv;
            if (fast){
                av[0]=m*e1s; av[1]=m*e2s; av[2]=m*e3s; av[3]=m*e4s;
                m *= e4s;
            } else {
#pragma unroll
                for (int k=0;k<4;++k) av[k] = __builtin_amdgcn_exp2f(sdt*ac2[g*4+k]);
            }
#pragma unroll
            for (int k=0;k<4;++k) hv[k] = h[g*4+k];
            *(f32x4*)&Aprod[o+4*g] = av;
            *(f32x4*)&Hend[o+4*g]  = hv;
        }
    }
}

// pass2: sequential combine (both dirs); carry-in written IN PLACE into Aprod
__global__ __launch_bounds__(256)
void scan2_k(float* __restrict__ Aprod, const float* __restrict__ Hend)
{
    int idx = blockIdx.x*256 + threadIdx.x;
    if (idx >= 2*BB*DINNER*DSTATE) return;
    int dir = idx / (BB*DINNER*DSTATE);
    int rem = idx - dir*(BB*DINNER*DSTATE);
    int b = rem / (DINNER*DSTATE);
    int ds = rem % (DINNER*DSTATE);
    long base = (long)dir*S_AP;
    float h = 0.f;
    for (int j=0;j<NCH;++j){
        long o = base + (long)(b*NCH+j)*DINNER*DSTATE + ds;
        float ap = Aprod[o];
        float he = Hend[o];
        Aprod[o] = h;
        h = ap*h + he;
    }
}

// ----------------------------------------------------------------------------
extern "C" void kernel_launch(void* const* d_in, const int* in_sizes, int n_in,
                              void* d_out, int out_size, void* d_ws, size_t ws_size,
                              hipStream_t stream)
{
    const float* x       = (const float*)d_in[0];
    const int*   sidx    = (const int*)  d_in[1];
    const float* norm_g  = (const float*)d_in[2];
    const float* norm_b  = (const float*)d_in[3];
    const float* fuse_w1 = (const float*)d_in[4];
    const float* fuse_b1 = (const float*)d_in[5];
    const float* fuse_w2 = (const float*)d_in[6];
    const float* fuse_b2 = (const float*)d_in[7];
    const float* f_in_w   = (const float*)d_in[8];
    const float* f_conv_w = (const float*)d_in[9];
    const float* f_conv_b = (const float*)d_in[10];
    const float* f_xproj  = (const float*)d_in[11];
    const float* f_dt_w   = (const float*)d_in[12];
    const float* f_dt_b   = (const float*)d_in[13];
    const float* f_A_log  = (const float*)d_in[14];
    const float* f_Dp     = (const float*)d_in[15];
    const float* f_out_w  = (const float*)d_in[16];
    const float* b_in_w   = (const float*)d_in[17];
    const float* b_conv_w = (const float*)d_in[18];
    const float* b_conv_b = (const float*)d_in[19];
    const float* b_xproj  = (const float*)d_in[20];
    const float* b_dt_w   = (const float*)d_in[21];
    const float* b_dt_b   = (const float*)d_in[22];
    const float* b_A_log  = (const float*)d_in[23];
    const float* b_Dp     = (const float*)d_in[24];
    const float* b_out_w  = (const float*)d_in[25];
    float* out = (float*)d_out;

    // ---- workspace layout (float units) ----
    float* ws    = (float*)d_ws;
    bf16_t* xn   = (bf16_t*)ws;                        // 7,077,888 bf16 (reused as xcR dir0)
    bf16_t* xz   = (bf16_t*)(ws + 3538944);            // 2 x 14,155,776 bf16 (TILED 1536)
    bf16_t* xc   = (bf16_t*)(ws + 17694720);           // 2 x 7,077,888 bf16  (TILED 768)
    bf16_t* dtb  = (bf16_t*)(ws + 24772608);           // 2 x 7,077,888 bf16  (TILED 768)
    float* bc    = ws + 31850496;                      // 2 x 294,912 fl
    bf16_t* yb   = (bf16_t*)(ws + 32440320);           // 2 x 7,077,888 bf16  ([t][d])
    bf16_t* h1   = (bf16_t*)(ws + 39518208);           // 7,077,888 bf16 (first: xcR dir1)
    float* Aprod = ws + 43057152;                      // 2 x 2,359,296 fl
    float* Hend  = ws + 47775744;                      // 2 x 2,359,296 fl
    bf16_t* wbf  = (bf16_t*)(ws + 52494336);           // 7,716,864 bf16
    int* rev_f   = (int*)(ws + 56352768);              // 2304
    int* rev_b   = rev_f + 2304;                       // 2304

    bf16_t* w_fin    = wbf + 0;
    bf16_t* w_bin    = wbf + 1179648;
    bf16_t* w_1      = wbf + 2359296;   // 768 x 1536
    bf16_t* w_2      = wbf + 3538944;   // 768 x 768
    bf16_t* w_fcombo = wbf + 4128768;   // 800 x 768
    bf16_t* w_bcombo = wbf + 4743168;   // 800 x 768
    bf16_t* foutT    = wbf + 5357568;   // 768 x 768 (f_out_w^T)
    bf16_t* boutT    = wbf + 5947392;   // 768 x 768
    bf16_t* Ccat     = wbf + 6537216;   // 768 x 1536 ([W1a@fout | W1b@bout])

    bf16_t* xcR0 = xn;                  // row-major xc, dir 0 (xn dead after in-proj)
    bf16_t* xcR1 = h1;                  // row-major xc, dir 1 (h1 written later)

    // ---- weight preprocessing ----
    wconv_k<<<16320, 256, 0, stream>>>(f_in_w, b_in_w, fuse_w1, fuse_w2,
                                       f_xproj + 48*768, b_xproj + 48*768, wbf);
    transp_k<<<dim3(24,24,2), 256, 0, stream>>>(f_out_w, b_out_w, foutT, boutT);
    inv_k<<<9, 256, 0, stream>>>(sidx, rev_f, rev_b);
    combo_k<<<768, 256, 0, stream>>>(f_dt_w, f_xproj, w_fcombo);
    combo_k<<<768, 256, 0, stream>>>(b_dt_w, b_xproj, w_bcombo);
    ln_k<<<MTOK, 256, 0, stream>>>(x, norm_g, norm_b, xn);
    gemm4_k<0,0,2><<<dim3(6,6,2), 256, 0, stream>>>(
        w_1, 768, 1536, foutT, boutT, 768, 768,
        Ccat, 0, nullptr, 0, 1536, 768, nullptr, nullptr, nullptr, nullptr,
        nullptr, nullptr);

    // ---- in-projection (both dirs) -> TILED xz ----
    gemm4_k<3,0,6><<<dim3(72,12,2), 256, 0, stream>>>(
        xn, 0, CC, w_fin, w_bin, 1536, 768,
        xz, S_XZ, nullptr, 0, 1536, 0, nullptr, nullptr, nullptr, sidx,
        nullptr, nullptr);
    // ---- depthwise conv (channel-major tiled; writes tiled + row-major) ----
    conv_k<<<dim3(1728, 2), 256, 0, stream>>>(
        xz, f_conv_w, b_conv_w, f_conv_b, b_conv_b, xc, xcR0, xcR1);
    // ---- combo projection: softplus(dt) TILED + B/C (both dirs) ----
    gemm4_k<0,0,7><<<dim3(72,7,2), 256, 0, stream>>>(
        xcR0, S_XCR, DINNER, w_fcombo, w_bcombo, 800, 768,
        dtb, S_DT, bc, S_BC, 768, 0, f_dt_b, b_dt_b, nullptr, nullptr,
        nullptr, nullptr);
    // ---- selective scan (both dirs, thread-per-channel, tiled b128 loads) ----
    scanp_k<1><<<dim3(BB*NCH*3,2), 256, 0, stream>>>(
        dtb, xc, bc, xz, f_A_log, b_A_log, f_Dp, b_Dp, Aprod, Hend, yb);
    scan2_k<<<384, 256, 0, stream>>>(Aprod, Hend);
    scanp_k<3><<<dim3(BB*NCH*3,2), 256, 0, stream>>>(
        dtb, xc, bc, xz, f_A_log, b_A_log, f_Dp, b_Dp, Aprod, Hend, yb);
    // ---- fused out-proj + fuse1 ----
    gemm4_k<4,0,3><<<dim3(72,6,1), 256, 0, stream>>>(
        yb, S_YB, DINNER, Ccat, Ccat, 768, 1536,
        h1, 0, nullptr, 0, 768, 0, fuse_b1, fuse_b1, nullptr, nullptr,
        rev_f, rev_b);
    // ---- fuse2 + residual (staged f32 epilogue) ----
    gemm4_k<0,0,4><<<dim3(72,6,1), 256, 0, stream>>>(
        h1, 0, DINNER, w_2, w_2, 768, 768,
        out, 0, nullptr, 0, 768, 0, fuse_b2, fuse_b2, x, nullptr,
        nullptr, nullptr);
}

// Round 10
// 490.292 us; speedup vs baseline: 1.1484x; 1.1484x over previous
//
#include <hip/hip_runtime.h>
#include <hip/hip_bf16.h>
#include <cmath>

#define BB 4
#define LL 2304
#define CC 768
#define DSTATE 16
#define DINNER 768
#define DTRANK 48
#define MTOK (BB*LL)          // 9216
#define NCH 48
#define LCH (LL/NCH)          // 48

// per-direction strides (element units)
#define S_XZ   14155776L
#define S_XC   7077888L
#define S_DT   7077888L
#define S_BC   294912L
#define S_YB   7077888L
#define S_AP   2359296L
#define S_XCR  79036416L      // gap between xcR dir0 (xn slot) and dir1 (h1 slot)

#define L2E 1.4426950408889634f

typedef __bf16 bf16_t;
typedef __bf16 bf16x8 __attribute__((ext_vector_type(8)));
typedef float  f32x4  __attribute__((ext_vector_type(4)));

__device__ __forceinline__ float silu_f(float v){ return v / (1.0f + __expf(-v)); }
__device__ __forceinline__ float softplus_f(float v){
    return fmaxf(v,0.f) + __logf(1.0f + __expf(-fabsf(v)));
}

typedef __attribute__((address_space(3))) void  lds_vt;
typedef __attribute__((address_space(1))) void  gbl_vt;
__device__ __forceinline__ void async_copy16(const void* g, void* l){
    __builtin_amdgcn_global_load_lds((const gbl_vt*)g, (lds_vt*)l, 16, 0, 0);
}

// TILED time-contiguous layout for scan operands:
//   X[tb][Ndim][8], element (r,n) at ((r>>3)*Ndim + n)*8 + (r&7).
// PRE-PERMUTED buffers (R10): producers scatter rows by the scan permutation
// once, so the downstream GEMMs read SEQUENTIAL rows (R9 post-mortem: the
// scattered gathers re-fetch each A row per n-tile, mostly L2-missing, and
// the GEMMs are latency-bound).

// ---------------- weight fp32 -> bf16 conversion ----------------------------
__global__ __launch_bounds__(256)
void wconv_k(const float* __restrict__ a0, const float* __restrict__ a1,
             const float* __restrict__ a2, const float* __restrict__ a3,
             const float* __restrict__ a4, const float* __restrict__ a5,
             bf16_t* __restrict__ dst)
{
    const int cum[7]  = {0,1179648,2359296,3538944,4128768,4153344,4177920};
    const int dofs[6] = {0,1179648,2359296,3538944,4718592,5332992};
    const float* srcs[6] = {a0,a1,a2,a3,a4,a5};
    int idx = blockIdx.x*256 + threadIdx.x;
    if (idx >= 4177920) return;
    int seg = 0;
    while (idx >= cum[seg+1]) ++seg;
    dst[dofs[seg] + idx - cum[seg]] = (bf16_t)srcs[seg][idx - cum[seg]];
}

// ---------------- transpose+convert 768x768 fp32 -> bf16 (dst = src^T) ------
__global__ __launch_bounds__(256)
void transp_k(const float* __restrict__ s0, const float* __restrict__ s1,
              bf16_t* __restrict__ d0, bf16_t* __restrict__ d1)
{
    __shared__ float tile[32][33];
    const float* src = blockIdx.z ? s1 : s0;
    bf16_t* dst = blockIdx.z ? d1 : d0;
    int c0 = blockIdx.y*32, d0c = blockIdx.x*32;
    int tx = threadIdx.x & 31, ty = threadIdx.x >> 5;   // ty 0..7
#pragma unroll
    for (int r=0;r<4;++r)
        tile[ty+8*r][tx] = src[(long)(c0+ty+8*r)*768 + d0c+tx];
    __syncthreads();
#pragma unroll
    for (int r=0;r<4;++r)
        dst[(long)(d0c+ty+8*r)*768 + c0+tx] = (bf16_t)tile[tx][ty+8*r];
}

// ---------------- inverse permutations ---------------------------------------
__global__ __launch_bounds__(256)
void inv_k(const int* __restrict__ sidx, int* __restrict__ rf, int* __restrict__ rb)
{
    int t = blockIdx.x*256 + threadIdx.x;
    if (t >= LL) return;
    rf[sidx[t]] = t;
    rb[sidx[LL-1-t]] = t;
}

// ---------------- combo weight: dst[n*768+k] = sum_r dtw[n*48+r]*xproj[r*768+k]
__global__ __launch_bounds__(256)
void combo_k(const float* __restrict__ dtw, const float* __restrict__ xproj,
             bf16_t* __restrict__ dst)
{
    __shared__ float row[48];
    int n = blockIdx.x;
    if (threadIdx.x < 48) row[threadIdx.x] = dtw[n*48 + threadIdx.x];
    __syncthreads();
#pragma unroll
    for (int kk=0; kk<3; ++kk){
        int k = threadIdx.x + 256*kk;
        float s = 0.f;
#pragma unroll 8
        for (int r=0; r<48; ++r) s += row[r]*xproj[r*768 + k];
        dst[n*768 + k] = (bf16_t)s;
    }
}

// ---------------- LayerNorm (per token, C=768) -> bf16, PERMUTED write ------
// Writes xn_perm[bo + rev_f[t]] = normalized(x[bo + t]) so the in-proj GEMM
// reads sequential rows (dir0 ascending, dir1 descending).
__global__ __launch_bounds__(256)
void ln_k(const float* __restrict__ x, const float* __restrict__ g,
          const float* __restrict__ bta, const int* __restrict__ rf,
          bf16_t* __restrict__ xn)
{
    int row = blockIdx.x;
    const float* xr = x + (long)row*CC;
    int tid = threadIdx.x;
    float v[3];
#pragma unroll
    for (int r=0;r<3;++r) v[r] = xr[tid + 256*r];
    float s  = v[0]+v[1]+v[2];
    float s2 = v[0]*v[0]+v[1]*v[1]+v[2]*v[2];
    __shared__ float red[8];
    for (int o=32;o;o>>=1){ s += __shfl_down(s,o); s2 += __shfl_down(s2,o); }
    int wv = tid>>6, ln = tid&63;
    if (ln==0){ red[wv]=s; red[4+wv]=s2; }
    __syncthreads();
    if (tid==0){
        red[0] = red[0]+red[1]+red[2]+red[3];
        red[4] = red[4]+red[5]+red[6]+red[7];
    }
    __syncthreads();
    float mu  = red[0]*(1.0f/CC);
    float var = red[4]*(1.0f/CC) - mu*mu;
    float rstd = rsqrtf(var + 1e-6f);
    int t = row % LL;
    long drow = (long)(row - t) + rf[t];
#pragma unroll
    for (int r=0;r<3;++r){
        int c = tid + 256*r;
        xn[drow*CC + c] = (bf16_t)((v[r]-mu)*rstd*g[c] + bta[c]);
    }
}

// ---------------- depthwise causal conv (k=4) + silu, tiled layout ----------
__global__ __launch_bounds__(256)
void conv_k(const bf16_t* __restrict__ xzT, const float* __restrict__ cw0,
            const float* __restrict__ cw1, const float* __restrict__ cb0,
            const float* __restrict__ cb1, bf16_t* __restrict__ xcT,
            bf16_t* __restrict__ xcR0, bf16_t* __restrict__ xcR1)
{
    const int dir = blockIdx.y;
    const bf16_t* src = xzT + (long)dir*S_XZ;
    bf16_t* dstT = xcT + (long)dir*S_XC;
    bf16_t* dstR = dir ? xcR1 : xcR0;
    const float* cw = dir ? cw1 : cw0;
    const float* cb = dir ? cb1 : cb0;
    int idx = blockIdx.x*256 + threadIdx.x;     // 768 * 576
    int d = idx % 768;                          // consecutive lanes -> consecutive d
    int chunk = idx / 768;                      // 0..575  (16-t chunks)
    int tb = chunk*2;
    int r0 = chunk*16;

    bf16x8 c0 = *(const bf16x8*)&src[((long)tb*1536 + d)*8];
    bf16x8 c1 = *(const bf16x8*)&src[((long)(tb+1)*1536 + d)*8];
    float xm3, xm2, xm1;
    if (r0 % LL){
        bf16x8 pv = *(const bf16x8*)&src[((long)(tb-1)*1536 + d)*8];
        xm3=(float)pv[5]; xm2=(float)pv[6]; xm1=(float)pv[7];
    } else { xm3=0.f; xm2=0.f; xm1=0.f; }

    float4 w = *(const float4*)&cw[d*4];
    float bz = cb[d];

    float xx[16];
#pragma unroll
    for (int u=0;u<8;++u){ xx[u]=(float)c0[u]; xx[8+u]=(float)c1[u]; }
    bf16x8 o0, o1;
#pragma unroll
    for (int u=0;u<16;++u){
        float cur = xx[u];
        float acc = bz + w.x*xm3 + w.y*xm2 + w.z*xm1 + w.w*cur;
        float r = silu_f(acc);
        if (u < 8) o0[u] = (bf16_t)r; else o1[u-8] = (bf16_t)r;
        xm3 = xm2; xm2 = xm1; xm1 = cur;
    }
    *(bf16x8*)&dstT[((long)tb*768 + d)*8]     = o0;
    *(bf16x8*)&dstT[((long)(tb+1)*768 + d)*8] = o1;
#pragma unroll
    for (int u=0;u<8;++u){
        dstR[(long)(r0+u)*DINNER + d]   = o0[u];
        dstR[(long)(r0+8+u)*DINNER + d] = o1[u];
    }
}

// ---------------- GEMM4: LDS-staged MFMA GEMM, 128x128 tile, BK=64 ----------
// GATHER: 0 none | 6 permuted-input: dir0 sequential rows, dir1 descending
//         rows (reverse view of the same pre-permuted buffer) |
//         7 sequential dual-phase A (k<768: A row r; k>=768: A+a_stride row r)
// EPI: 2 store bf16 (staged wide) | 3 gelu+bias->bf16 (staged) |
//      4 bias+resid->f32 scalar | 6 bf16 TRANSPOSED-TILED (staged) |
//      7 softplus TRANSPOSED-TILED + bc scalar
template<int GATHER, int SCATTER, int EPI>
__global__ __launch_bounds__(256)
void gemm4_k(const bf16_t* __restrict__ A, long a_stride, int lda,
             const bf16_t* __restrict__ W0, const bf16_t* __restrict__ W1,
             int N, int K,
             void* __restrict__ out1, long o1_stride,
             void* __restrict__ out2, long o2_stride,
             int ldc, int ccol_stride,
             const float* __restrict__ bias0, const float* __restrict__ bias1,
             const float* __restrict__ resid,
             const int* __restrict__ sidx,
             const int* __restrict__ ridx0, const int* __restrict__ ridx1)
{
    __shared__ __align__(16) bf16_t smem[2*128*64];   // As | Bs ; reused as Cs
    bf16_t* As = smem;
    bf16_t* Bs = smem + 128*64;

    const int tid  = threadIdx.x;
    const int lane = tid & 63;
    const int w    = tid >> 6;
    const int ln16 = lane & 15;
    const int q    = lane >> 4;
    const int dir  = blockIdx.z;

    const bf16_t* Ad = A + (long)dir*a_stride;
    const bf16_t* W  = dir ? W1 : W0;
    const float* bias = dir ? bias1 : bias0;

    const int m0 = blockIdx.x*128;
    const int n0 = blockIdx.y*128;

    const int srow = lane >> 3;
    const int csrc = (lane & 7) ^ srow;
    const bf16_t* gA[4]; const bf16_t* gA1[4]; const bf16_t* gB[4];
#pragma unroll
    for (int inst=0; inst<4; ++inst){
        int row = w*32 + inst*8 + srow;
        int r = m0 + row;
        if (GATHER == 7){
            gA[inst]  = A + (long)r*lda + csrc*8;
            gA1[inst] = A + a_stride + (long)r*lda + csrc*8;
        } else {
            int sr = r;
            if (GATHER == 6 && dir){
                int t = r % LL;
                sr = r - t + (LL-1-t);
            }
            gA[inst] = Ad + (long)sr*lda + csrc*8;
        }
        int n = n0 + row; if (n >= N) n = N-1;
        gB[inst] = W + (long)n*K + csrc*8;
    }

    f32x4 acc[4][4];
#pragma unroll
    for (int i=0;i<4;++i)
#pragma unroll
      for (int j=0;j<4;++j) acc[i][j] = (f32x4){0.f,0.f,0.f,0.f};

    const int e = ln16 & 7;
    const int ar_base = ((w>>1)*64 + ln16)*64;
    const int br_base = ((w&1)*64 + ln16)*64;

    for (int k0 = 0; k0 < K; k0 += 64){
#pragma unroll
        for (int inst=0; inst<4; ++inst){
            bf16_t* la = As + (w*256 + inst*64)*8;
            bf16_t* lb = Bs + (w*256 + inst*64)*8;
            const bf16_t* asrc;
            if (GATHER == 7)
                asrc = (k0 >= 768) ? (gA1[inst] + (k0 - 768)) : (gA[inst] + k0);
            else
                asrc = gA[inst] + k0;
            async_copy16(asrc, la);
            async_copy16(gB[inst] + k0, lb);
        }
        __syncthreads();
#pragma unroll
        for (int kk=0; kk<2; ++kk){
            const int ce = (((kk<<2)|q) ^ e)*8;
            bf16x8 af[4], bf[4];
#pragma unroll
            for (int i=0;i<4;++i) af[i] = *(const bf16x8*)&As[ar_base + i*16*64 + ce];
#pragma unroll
            for (int j=0;j<4;++j) bf[j] = *(const bf16x8*)&Bs[br_base + j*16*64 + ce];
#pragma unroll
            for (int i=0;i<4;++i)
#pragma unroll
              for (int j=0;j<4;++j)
                acc[i][j] = __builtin_amdgcn_mfma_f32_16x16x32_bf16(af[i], bf[j], acc[i][j], 0,0,0);
        }
        __syncthreads();
    }

    const int mw = (w>>1)*64;
    const int nw = (w&1)*64;
    const int ccolb = ccol_stride*dir;

    const bool staged = (EPI==2) || (EPI==3) || (EPI==6) ||
                        (EPI==7 && n0 < 768);
    if (staged){
        bf16_t* Cs = smem;
#pragma unroll
        for (int i=0;i<4;++i){
#pragma unroll
            for (int reg=0; reg<4; ++reg){
                int rowl = mw + i*16 + q*4 + reg;
#pragma unroll
                for (int j=0;j<4;++j){
                    int coll = nw + j*16 + ln16;
                    float v = acc[i][j][reg];
                    if (EPI==3){
                        v += bias[n0 + coll];
                        v = 0.5f*v*(1.0f + erff(v*0.70710678118654752f));
                    } else if (EPI==7){
                        v = softplus_f(v + bias[n0 + coll]);
                    }
                    Cs[rowl*128 + coll] = (bf16_t)v;
                }
            }
        }
        __syncthreads();
        bf16_t* o = (bf16_t*)out1 + (long)dir*o1_stride;
        if (EPI==6 || EPI==7){
            // transposed-tiled store: X[((r>>3)*ldc + n)*8 + (r&7)]
#pragma unroll
            for (int c=0;c<8;++c){
                int chunk = tid + 256*c;        // 0..2047
                int nb  = chunk & 127;          // lane-consecutive n
                int tbl = chunk >> 7;           // 0..15 t-block within tile
                bf16x8 v;
#pragma unroll
                for (int u=0;u<8;++u) v[u] = Cs[(tbl*8+u)*128 + nb];
                long base = ((long)(m0/8 + tbl)*ldc + (n0 + nb))*8;
                *(bf16x8*)&o[base] = v;
            }
        } else {
#pragma unroll
            for (int c=0;c<8;++c){
                int chunk = tid + 256*c;        // 0..2047
                int rowl = chunk >> 4;
                int coll = (chunk & 15)*8;
                int r = m0 + rowl;
                *(int4*)&o[(long)r*ldc + ccolb + n0 + coll] = *(const int4*)&Cs[rowl*128 + coll];
            }
        }
    } else {
        // ---- scalar epilogue (EPI 4, or EPI 7 bc-tile) ----
#pragma unroll
        for (int i=0;i<4;++i){
#pragma unroll
            for (int reg=0; reg<4; ++reg){
                int r = m0 + mw + i*16 + q*4 + reg;
#pragma unroll
                for (int j=0;j<4;++j){
                    int col = n0 + nw + j*16 + ln16;
                    if (col >= N) continue;
                    float v = acc[i][j][reg];
                    if (EPI==4){
                        v += bias[col] + resid[(long)r*CC + col];
                        ((float*)out1)[(long)r*ldc + col] = v;
                    } else { // EPI==7 bc tile (col in [768, 800))
                        ((float*)out2 + (long)dir*o2_stride)[(long)r*32 + (col-768)] = v;
                    }
                }
            }
        }
    }
}

// ---------------- selective scan v8: tiled b128 loads, permuted y write -----
// Register-light fast path (R8): ek[k]=e1^(k+1) from 5 live scalars + running
// group multiplier. R10: PASS3 writes y at its FINAL (un-permuted) position
// (row sidx[jp] dir0 / sidx[LL-1-jp] dir1; uniform scalar index per row, write
// stays 512B-coalesced) so fuse1 reads sequential rows.
template<int PASS>
__global__ __launch_bounds__(256)
void scanp_k(const bf16_t* __restrict__ dtp, const bf16_t* __restrict__ xcp,
             const float* __restrict__ bcp, const bf16_t* __restrict__ xzp,
             const float* __restrict__ Al0, const float* __restrict__ Al1,
             const float* __restrict__ Dp0, const float* __restrict__ Dp1,
             float* __restrict__ Aprod, float* __restrict__ Hend,
             bf16_t* __restrict__ yout, const int* __restrict__ sidx)
{
    __shared__ __align__(16) float s_bc[LCH*32];   // 6144 B

    const int dir = blockIdx.y;
    int blk = blockIdx.x;
    const int dblk = blk % 3; int tmp = blk / 3;
    const int j = tmp % NCH; const int b = tmp / NCH;
    const int tid = threadIdx.x;
    const long tbase = (long)b*LL + (long)j*LCH;
    const long tb0 = tbase >> 3;
    const int d = dblk*256 + tid;

    const float* gbc = bcp + dir*S_BC + tbase*32;
    async_copy16(gbc + tid*4, s_bc + tid*4);
    if (tid < 128) async_copy16(gbc + (256+tid)*4, s_bc + (256+tid)*4);

    const float* Al = dir ? Al1 : Al0;
    float ac2[16]; bool fast = true;
#pragma unroll
    for (int k=0;k<16;++k){
        float a = -__expf(Al[d*DSTATE + k]);
        fast = fast && (fabsf(a + (float)(k+1)) < 1e-3f*(float)(k+1));
        ac2[k] = a * L2E;
    }

    const bf16_t* gdt = dtp + dir*S_DT + (tb0*768  + d)*8;
    const bf16_t* gxc = xcp + dir*S_XC + (tb0*768  + d)*8;
    const bf16_t* gz  = xzp + dir*S_XZ + (tb0*1536 + 768 + d)*8;
    bf16_t* gyb = yout + dir*S_YB + (long)b*LL*DINNER + d;

    const long o = dir*S_AP + ((long)(b*NCH + j)*DINNER + d)*DSTATE;

    float h[16];
    float dpv = 0.f;
    if (PASS==3){
#pragma unroll
        for (int g=0; g<4; ++g){
            f32x4 hv = *(const f32x4*)&Aprod[o + 4*g];
#pragma unroll
            for (int k=0;k<4;++k) h[g*4+k] = hv[k];
        }
        dpv = (dir ? Dp1 : Dp0)[d];
    } else {
#pragma unroll
        for (int k=0;k<16;++k) h[k] = 0.f;
    }
    float sdt = 0.f;

    __syncthreads();   // s_bc ready

#pragma unroll 1
    for (int cc=0; cc<LCH/8; ++cc){
        bf16x8 vdt = *(const bf16x8*)&gdt[(long)cc*6144];      // 768*8
        bf16x8 vxc = *(const bf16x8*)&gxc[(long)cc*6144];
        bf16x8 vz;
        if (PASS==3) vz = *(const bf16x8*)&gz[(long)cc*12288]; // 1536*8
#pragma unroll
        for (int u=0; u<8; ++u){
            const int t = cc*8 + u;
            float dt = (float)vdt[u];
            float xv = (float)vxc[u];
            float c = dt*xv;
            if (PASS==1) sdt += dt;
            const float* bcr = &s_bc[t*32];
            float p = 0.f;
            if (fast){
                float e1 = __builtin_amdgcn_exp2f(-L2E*dt);
                float e2 = e1*e1, e3 = e2*e1, e4 = e2*e2;
                float m = 1.0f;
#pragma unroll
                for (int g=0; g<4; ++g){
                    f32x4 Bv = *(const f32x4*)&bcr[g*4];
                    h[g*4+0] = (m*e1)*h[g*4+0] + c*Bv[0];
                    h[g*4+1] = (m*e2)*h[g*4+1] + c*Bv[1];
                    h[g*4+2] = (m*e3)*h[g*4+2] + c*Bv[2];
                    h[g*4+3] = (m*e4)*h[g*4+3] + c*Bv[3];
                    if (PASS==3){
                        f32x4 Cv = *(const f32x4*)&bcr[16 + g*4];
                        p += h[g*4+0]*Cv[0] + h[g*4+1]*Cv[1]
                           + h[g*4+2]*Cv[2] + h[g*4+3]*Cv[3];
                    }
                    m *= e4;
                }
            } else {
#pragma unroll
                for (int g=0; g<4; ++g){
                    f32x4 Bv = *(const f32x4*)&bcr[g*4];
#pragma unroll
                    for (int k=0;k<4;++k)
                        h[g*4+k] = __builtin_amdgcn_exp2f(dt*ac2[g*4+k])*h[g*4+k] + c*Bv[k];
                    if (PASS==3){
                        f32x4 Cv = *(const f32x4*)&bcr[16 + g*4];
                        p += h[g*4+0]*Cv[0] + h[g*4+1]*Cv[1]
                           + h[g*4+2]*Cv[2] + h[g*4+3]*Cv[3];
                    }
                }
            }
            if (PASS==3){
                float zv = (float)vz[u];
                int jp = j*LCH + t;
                int prow = dir ? sidx[LL-1-jp] : sidx[jp];
                gyb[(long)prow*DINNER] = (bf16_t)((p + dpv*xv) * silu_f(zv));
            }
        }
    }

    if (PASS==1){
        float e1s = __builtin_amdgcn_exp2f(-L2E*sdt);
        float e2s = e1s*e1s, e3s = e2s*e1s, e4s = e2s*e2s;
        float m = 1.0f;
#pragma unroll
        for (int g=0; g<4; ++g){
            f32x4 av, hv;
            if (fast){
                av[0]=m*e1s; av[1]=m*e2s; av[2]=m*e3s; av[3]=m*e4s;
                m *= e4s;
            } else {
#pragma unroll
                for (int k=0;k<4;++k) av[k] = __builtin_amdgcn_exp2f(sdt*ac2[g*4+k]);
            }
#pragma unroll
            for (int k=0;k<4;++k) hv[k] = h[g*4+k];
            *(f32x4*)&Aprod[o+4*g] = av;
            *(f32x4*)&Hend[o+4*g]  = hv;
        }
    }
}

// pass2: sequential combine (both dirs); carry-in written IN PLACE into Aprod
__global__ __launch_bounds__(256)
void scan2_k(float* __restrict__ Aprod, const float* __restrict__ Hend)
{
    int idx = blockIdx.x*256 + threadIdx.x;
    if (idx >= 2*BB*DINNER*DSTATE) return;
    int dir = idx / (BB*DINNER*DSTATE);
    int rem = idx - dir*(BB*DINNER*DSTATE);
    int b = rem / (DINNER*DSTATE);
    int ds = rem % (DINNER*DSTATE);
    long base = (long)dir*S_AP;
    float h = 0.f;
    for (int j=0;j<NCH;++j){
        long o = base + (long)(b*NCH+j)*DINNER*DSTATE + ds;
        float ap = Aprod[o];
        float he = Hend[o];
        Aprod[o] = h;
        h = ap*h + he;
    }
}

// ----------------------------------------------------------------------------
extern "C" void kernel_launch(void* const* d_in, const int* in_sizes, int n_in,
                              void* d_out, int out_size, void* d_ws, size_t ws_size,
                              hipStream_t stream)
{
    const float* x       = (const float*)d_in[0];
    const int*   sidx    = (const int*)  d_in[1];
    const float* norm_g  = (const float*)d_in[2];
    const float* norm_b  = (const float*)d_in[3];
    const float* fuse_w1 = (const float*)d_in[4];
    const float* fuse_b1 = (const float*)d_in[5];
    const float* fuse_w2 = (const float*)d_in[6];
    const float* fuse_b2 = (const float*)d_in[7];
    const float* f_in_w   = (const float*)d_in[8];
    const float* f_conv_w = (const float*)d_in[9];
    const float* f_conv_b = (const float*)d_in[10];
    const float* f_xproj  = (const float*)d_in[11];
    const float* f_dt_w   = (const float*)d_in[12];
    const float* f_dt_b   = (const float*)d_in[13];
    const float* f_A_log  = (const float*)d_in[14];
    const float* f_Dp     = (const float*)d_in[15];
    const float* f_out_w  = (const float*)d_in[16];
    const float* b_in_w   = (const float*)d_in[17];
    const float* b_conv_w = (const float*)d_in[18];
    const float* b_conv_b = (const float*)d_in[19];
    const float* b_xproj  = (const float*)d_in[20];
    const float* b_dt_w   = (const float*)d_in[21];
    const float* b_dt_b   = (const float*)d_in[22];
    const float* b_A_log  = (const float*)d_in[23];
    const float* b_Dp     = (const float*)d_in[24];
    const float* b_out_w  = (const float*)d_in[25];
    float* out = (float*)d_out;

    // ---- workspace layout (float units) ----
    float* ws    = (float*)d_ws;
    bf16_t* xn   = (bf16_t*)ws;                        // 7,077,888 bf16 (PERMUTED; reused as xcR dir0)
    bf16_t* xz   = (bf16_t*)(ws + 3538944);            // 2 x 14,155,776 bf16 (TILED 1536)
    bf16_t* xc   = (bf16_t*)(ws + 17694720);           // 2 x 7,077,888 bf16  (TILED 768)
    bf16_t* dtb  = (bf16_t*)(ws + 24772608);           // 2 x 7,077,888 bf16  (TILED 768)
    float* bc    = ws + 31850496;                      // 2 x 294,912 fl
    bf16_t* yb   = (bf16_t*)(ws + 32440320);           // 2 x 7,077,888 bf16  (PERMUTED [t][d])
    bf16_t* h1   = (bf16_t*)(ws + 39518208);           // 7,077,888 bf16 (first: xcR dir1)
    float* Aprod = ws + 43057152;                      // 2 x 2,359,296 fl
    float* Hend  = ws + 47775744;                      // 2 x 2,359,296 fl
    bf16_t* wbf  = (bf16_t*)(ws + 52494336);           // 7,716,864 bf16
    int* rev_f   = (int*)(ws + 56352768);              // 2304
    int* rev_b   = rev_f + 2304;                       // 2304

    bf16_t* w_fin    = wbf + 0;
    bf16_t* w_bin    = wbf + 1179648;
    bf16_t* w_1      = wbf + 2359296;   // 768 x 1536
    bf16_t* w_2      = wbf + 3538944;   // 768 x 768
    bf16_t* w_fcombo = wbf + 4128768;   // 800 x 768
    bf16_t* w_bcombo = wbf + 4743168;   // 800 x 768
    bf16_t* foutT    = wbf + 5357568;   // 768 x 768 (f_out_w^T)
    bf16_t* boutT    = wbf + 5947392;   // 768 x 768
    bf16_t* Ccat     = wbf + 6537216;   // 768 x 1536 ([W1a@fout | W1b@bout])

    bf16_t* xcR0 = xn;                  // row-major xc, dir 0 (xn dead after in-proj)
    bf16_t* xcR1 = h1;                  // row-major xc, dir 1 (h1 written later)

    // ---- weight preprocessing ----
    wconv_k<<<16320, 256, 0, stream>>>(f_in_w, b_in_w, fuse_w1, fuse_w2,
                                       f_xproj + 48*768, b_xproj + 48*768, wbf);
    transp_k<<<dim3(24,24,2), 256, 0, stream>>>(f_out_w, b_out_w, foutT, boutT);
    inv_k<<<9, 256, 0, stream>>>(sidx, rev_f, rev_b);
    combo_k<<<768, 256, 0, stream>>>(f_dt_w, f_xproj, w_fcombo);
    combo_k<<<768, 256, 0, stream>>>(b_dt_w, b_xproj, w_bcombo);
    ln_k<<<MTOK, 256, 0, stream>>>(x, norm_g, norm_b, rev_f, xn);
    gemm4_k<0,0,2><<<dim3(6,6,2), 256, 0, stream>>>(
        w_1, 768, 1536, foutT, boutT, 768, 768,
        Ccat, 0, nullptr, 0, 1536, 768, nullptr, nullptr, nullptr, nullptr,
        nullptr, nullptr);

    // ---- in-projection (both dirs, sequential reads of permuted xn) ----
    gemm4_k<6,0,6><<<dim3(72,12,2), 256, 0, stream>>>(
        xn, 0, CC, w_fin, w_bin, 1536, 768,
        xz, S_XZ, nullptr, 0, 1536, 0, nullptr, nullptr, nullptr, nullptr,
        nullptr, nullptr);
    // ---- depthwise conv (channel-major tiled; writes tiled + row-major) ----
    conv_k<<<dim3(1728, 2), 256, 0, stream>>>(
        xz, f_conv_w, b_conv_w, f_conv_b, b_conv_b, xc, xcR0, xcR1);
    // ---- combo projection: softplus(dt) TILED + B/C (both dirs) ----
    gemm4_k<0,0,7><<<dim3(72,7,2), 256, 0, stream>>>(
        xcR0, S_XCR, DINNER, w_fcombo, w_bcombo, 800, 768,
        dtb, S_DT, bc, S_BC, 768, 0, f_dt_b, b_dt_b, nullptr, nullptr,
        nullptr, nullptr);
    // ---- selective scan (both dirs, tiled b128 loads, permuted y write) ----
    scanp_k<1><<<dim3(BB*NCH*3,2), 256, 0, stream>>>(
        dtb, xc, bc, xz, f_A_log, b_A_log, f_Dp, b_Dp, Aprod, Hend, yb, sidx);
    scan2_k<<<384, 256, 0, stream>>>(Aprod, Hend);
    scanp_k<3><<<dim3(BB*NCH*3,2), 256, 0, stream>>>(
        dtb, xc, bc, xz, f_A_log, b_A_log, f_Dp, b_Dp, Aprod, Hend, yb, sidx);
    // ---- fused out-proj + fuse1 (sequential dual-phase reads of permuted yb) ----
    gemm4_k<7,0,3><<<dim3(72,6,1), 256, 0, stream>>>(
        yb, S_YB, DINNER, Ccat, Ccat, 768, 1536,
        h1, 0, nullptr, 0, 768, 0, fuse_b1, fuse_b1, nullptr, nullptr,
        nullptr, nullptr);
    // ---- fuse2 + residual ----
    gemm4_k<0,0,4><<<dim3(72,6,1), 256, 0, stream>>>(
        h1, 0, DINNER, w_2, w_2, 768, 768,
        out, 0, nullptr, 0, 768, 0, fuse_b2, fuse_b2, x, nullptr,
        nullptr, nullptr);
}

// Round 11
// 472.295 us; speedup vs baseline: 1.1921x; 1.0381x over previous
//
#include <hip/hip_runtime.h>
#include <hip/hip_bf16.h>
#include <cmath>

#define BB 4
#define LL 2304
#define CC 768
#define DSTATE 16
#define DINNER 768
#define DTRANK 48
#define MTOK (BB*LL)          // 9216
#define NCH 48
#define LCH (LL/NCH)          // 48

// per-direction strides (element units)
#define S_XZ   14155776L
#define S_XC   7077888L
#define S_DT   7077888L
#define S_BC   294912L
#define S_YB   7077888L
#define S_AP   2359296L
#define S_XCR  79036416L      // gap between xcR dir0 (xn slot) and dir1 (h1 slot)

#define L2E 1.4426950408889634f

typedef __bf16 bf16_t;
typedef __bf16 bf16x8 __attribute__((ext_vector_type(8)));
typedef float  f32x4  __attribute__((ext_vector_type(4)));

__device__ __forceinline__ float silu_f(float v){ return v / (1.0f + __expf(-v)); }
__device__ __forceinline__ float softplus_f(float v){
    return fmaxf(v,0.f) + __logf(1.0f + __expf(-fabsf(v)));
}

typedef __attribute__((address_space(3))) void  lds_vt;
typedef __attribute__((address_space(1))) void  gbl_vt;
__device__ __forceinline__ void async_copy16(const void* g, void* l){
    __builtin_amdgcn_global_load_lds((const gbl_vt*)g, (lds_vt*)l, 16, 0, 0);
}

// TILED time-contiguous layout for scan operands:
//   X[tb][Ndim][8], element (r,n) at ((r>>3)*Ndim + n)*8 + (r&7).
// PRE-PERMUTED buffers: producers place rows in scan order once, so the
// downstream GEMMs read SEQUENTIAL rows.

// ---------------- merged preprocessing kernel (R11) -------------------------
// All 6 preprocessing ops are mutually independent; one launch replaces the
// serialized chain (each small kernel underutilized + paid launch/drain tail).
// Block ranges: [0,9216) ln | [9216,25536) wconv | [25536,26688) transp |
// [26688,28224) combo.  inv_k deleted: ln gather-reads x[bo+sidx[p]] and
// writes xn[bo+p] SEQUENTIALLY (equivalent to the rev_f scatter, same bytes).
__global__ __launch_bounds__(256)
void prep_k(const float* __restrict__ x, const float* __restrict__ g,
            const float* __restrict__ bta, const int* __restrict__ sidx,
            bf16_t* __restrict__ xn,
            const float* __restrict__ a0, const float* __restrict__ a1,
            const float* __restrict__ a2, const float* __restrict__ a3,
            const float* __restrict__ a4, const float* __restrict__ a5,
            bf16_t* __restrict__ wdst,
            const float* __restrict__ t0s, const float* __restrict__ t1s,
            bf16_t* __restrict__ t0d, bf16_t* __restrict__ t1d,
            const float* __restrict__ fdtw, const float* __restrict__ fxp,
            const float* __restrict__ bdtw, const float* __restrict__ bxp,
            bf16_t* __restrict__ fcombo, bf16_t* __restrict__ bcombo)
{
    const int bid = blockIdx.x;
    const int tid = threadIdx.x;

    if (bid < 9216){
        // ---- LayerNorm, permuted via gather-read, sequential write ----
        int row = bid;
        int p = row % LL;
        long srow = (long)(row - p) + sidx[p];
        const float* xr = x + srow*CC;
        float v[3];
#pragma unroll
        for (int r=0;r<3;++r) v[r] = xr[tid + 256*r];
        float s  = v[0]+v[1]+v[2];
        float s2 = v[0]*v[0]+v[1]*v[1]+v[2]*v[2];
        __shared__ float red[8];
        for (int o=32;o;o>>=1){ s += __shfl_down(s,o); s2 += __shfl_down(s2,o); }
        int wv = tid>>6, ln = tid&63;
        if (ln==0){ red[wv]=s; red[4+wv]=s2; }
        __syncthreads();
        if (tid==0){
            red[0] = red[0]+red[1]+red[2]+red[3];
            red[4] = red[4]+red[5]+red[6]+red[7];
        }
        __syncthreads();
        float mu  = red[0]*(1.0f/CC);
        float var = red[4]*(1.0f/CC) - mu*mu;
        float rstd = rsqrtf(var + 1e-6f);
#pragma unroll
        for (int r=0;r<3;++r){
            int c = tid + 256*r;
            xn[(long)row*CC + c] = (bf16_t)((v[r]-mu)*rstd*g[c] + bta[c]);
        }
    } else if (bid < 25536){
        // ---- weight fp32 -> bf16 conversion ----
        const int cum[7]  = {0,1179648,2359296,3538944,4128768,4153344,4177920};
        const int dofs[6] = {0,1179648,2359296,3538944,4718592,5332992};
        const float* srcs[6] = {a0,a1,a2,a3,a4,a5};
        int idx = (bid-9216)*256 + tid;
        if (idx >= 4177920) return;
        int seg = 0;
        while (idx >= cum[seg+1]) ++seg;
        wdst[dofs[seg] + idx - cum[seg]] = (bf16_t)srcs[seg][idx - cum[seg]];
    } else if (bid < 26688){
        // ---- transpose+convert 768x768 fp32 -> bf16 (dst = src^T) ----
        __shared__ float tile[32][33];
        int tix = bid - 25536;              // 0..1151
        int bx = tix % 24, by = (tix/24) % 24, bz = tix / 576;
        const float* src = bz ? t1s : t0s;
        bf16_t* dst = bz ? t1d : t0d;
        int c0 = by*32, d0c = bx*32;
        int tx = tid & 31, ty = tid >> 5;   // ty 0..7
#pragma unroll
        for (int r=0;r<4;++r)
            tile[ty+8*r][tx] = src[(long)(c0+ty+8*r)*768 + d0c+tx];
        __syncthreads();
#pragma unroll
        for (int r=0;r<4;++r)
            dst[(long)(d0c+ty+8*r)*768 + c0+tx] = (bf16_t)tile[tx][ty+8*r];
    } else {
        // ---- combo weight: dst[n*768+k] = sum_r dtw[n*48+r]*xproj[r*768+k] --
        __shared__ float row[48];
        int cidx = bid - 26688;             // 0..1535
        int n = cidx & 767;
        const float* dtw = (cidx < 768) ? fdtw : bdtw;
        const float* xproj = (cidx < 768) ? fxp : bxp;
        bf16_t* dst = (cidx < 768) ? fcombo : bcombo;
        if (tid < 48) row[tid] = dtw[n*48 + tid];
        __syncthreads();
#pragma unroll
        for (int kk=0; kk<3; ++kk){
            int k = tid + 256*kk;
            float s = 0.f;
#pragma unroll 8
            for (int r=0; r<48; ++r) s += row[r]*xproj[r*768 + k];
            dst[n*768 + k] = (bf16_t)s;
        }
    }
}

// ---------------- depthwise causal conv (k=4) + silu, tiled layout ----------
__global__ __launch_bounds__(256)
void conv_k(const bf16_t* __restrict__ xzT, const float* __restrict__ cw0,
            const float* __restrict__ cw1, const float* __restrict__ cb0,
            const float* __restrict__ cb1, bf16_t* __restrict__ xcT,
            bf16_t* __restrict__ xcR0, bf16_t* __restrict__ xcR1)
{
    const int dir = blockIdx.y;
    const bf16_t* src = xzT + (long)dir*S_XZ;
    bf16_t* dstT = xcT + (long)dir*S_XC;
    bf16_t* dstR = dir ? xcR1 : xcR0;
    const float* cw = dir ? cw1 : cw0;
    const float* cb = dir ? cb1 : cb0;
    int idx = blockIdx.x*256 + threadIdx.x;     // 768 * 576
    int d = idx % 768;                          // consecutive lanes -> consecutive d
    int chunk = idx / 768;                      // 0..575  (16-t chunks)
    int tb = chunk*2;
    int r0 = chunk*16;

    bf16x8 c0 = *(const bf16x8*)&src[((long)tb*1536 + d)*8];
    bf16x8 c1 = *(const bf16x8*)&src[((long)(tb+1)*1536 + d)*8];
    float xm3, xm2, xm1;
    if (r0 % LL){
        bf16x8 pv = *(const bf16x8*)&src[((long)(tb-1)*1536 + d)*8];
        xm3=(float)pv[5]; xm2=(float)pv[6]; xm1=(float)pv[7];
    } else { xm3=0.f; xm2=0.f; xm1=0.f; }

    float4 w = *(const float4*)&cw[d*4];
    float bz = cb[d];

    float xx[16];
#pragma unroll
    for (int u=0;u<8;++u){ xx[u]=(float)c0[u]; xx[8+u]=(float)c1[u]; }
    bf16x8 o0, o1;
#pragma unroll
    for (int u=0;u<16;++u){
        float cur = xx[u];
        float acc = bz + w.x*xm3 + w.y*xm2 + w.z*xm1 + w.w*cur;
        float r = silu_f(acc);
        if (u < 8) o0[u] = (bf16_t)r; else o1[u-8] = (bf16_t)r;
        xm3 = xm2; xm2 = xm1; xm1 = cur;
    }
    *(bf16x8*)&dstT[((long)tb*768 + d)*8]     = o0;
    *(bf16x8*)&dstT[((long)(tb+1)*768 + d)*8] = o1;
#pragma unroll
    for (int u=0;u<8;++u){
        dstR[(long)(r0+u)*DINNER + d]   = o0[u];
        dstR[(long)(r0+8+u)*DINNER + d] = o1[u];
    }
}

// ---------------- GEMM4: LDS-staged MFMA GEMM, 128x128 tile, BK=64 ----------
// GATHER: 0 none | 6 permuted-input: dir0 sequential rows, dir1 descending
//         rows (reverse view of the same pre-permuted buffer) |
//         7 sequential dual-phase A (k<768: A row r; k>=768: A+a_stride row r)
// EPI: 2 store bf16 (staged wide) | 3 gelu+bias->bf16 (staged) |
//      4 bias+resid->f32 scalar | 6 bf16 TRANSPOSED-TILED (staged) |
//      7 softplus TRANSPOSED-TILED + bc scalar
template<int GATHER, int SCATTER, int EPI>
__global__ __launch_bounds__(256)
void gemm4_k(const bf16_t* __restrict__ A, long a_stride, int lda,
             const bf16_t* __restrict__ W0, const bf16_t* __restrict__ W1,
             int N, int K,
             void* __restrict__ out1, long o1_stride,
             void* __restrict__ out2, long o2_stride,
             int ldc, int ccol_stride,
             const float* __restrict__ bias0, const float* __restrict__ bias1,
             const float* __restrict__ resid)
{
    __shared__ __align__(16) bf16_t smem[2*128*64];   // As | Bs ; reused as Cs
    bf16_t* As = smem;
    bf16_t* Bs = smem + 128*64;

    const int tid  = threadIdx.x;
    const int lane = tid & 63;
    const int w    = tid >> 6;
    const int ln16 = lane & 15;
    const int q    = lane >> 4;
    const int dir  = blockIdx.z;

    const bf16_t* Ad = A + (long)dir*a_stride;
    const bf16_t* W  = dir ? W1 : W0;
    const float* bias = dir ? bias1 : bias0;

    const int m0 = blockIdx.x*128;
    const int n0 = blockIdx.y*128;

    const int srow = lane >> 3;
    const int csrc = (lane & 7) ^ srow;
    const bf16_t* gA[4]; const bf16_t* gA1[4]; const bf16_t* gB[4];
#pragma unroll
    for (int inst=0; inst<4; ++inst){
        int row = w*32 + inst*8 + srow;
        int r = m0 + row;
        if (GATHER == 7){
            gA[inst]  = A + (long)r*lda + csrc*8;
            gA1[inst] = A + a_stride + (long)r*lda + csrc*8;
        } else {
            int sr = r;
            if (GATHER == 6 && dir){
                int t = r % LL;
                sr = r - t + (LL-1-t);
            }
            gA[inst] = Ad + (long)sr*lda + csrc*8;
        }
        int n = n0 + row; if (n >= N) n = N-1;
        gB[inst] = W + (long)n*K + csrc*8;
    }

    f32x4 acc[4][4];
#pragma unroll
    for (int i=0;i<4;++i)
#pragma unroll
      for (int j=0;j<4;++j) acc[i][j] = (f32x4){0.f,0.f,0.f,0.f};

    const int e = ln16 & 7;
    const int ar_base = ((w>>1)*64 + ln16)*64;
    const int br_base = ((w&1)*64 + ln16)*64;

    for (int k0 = 0; k0 < K; k0 += 64){
#pragma unroll
        for (int inst=0; inst<4; ++inst){
            bf16_t* la = As + (w*256 + inst*64)*8;
            bf16_t* lb = Bs + (w*256 + inst*64)*8;
            const bf16_t* asrc;
            if (GATHER == 7)
                asrc = (k0 >= 768) ? (gA1[inst] + (k0 - 768)) : (gA[inst] + k0);
            else
                asrc = gA[inst] + k0;
            async_copy16(asrc, la);
            async_copy16(gB[inst] + k0, lb);
        }
        __syncthreads();
#pragma unroll
        for (int kk=0; kk<2; ++kk){
            const int ce = (((kk<<2)|q) ^ e)*8;
            bf16x8 af[4], bf[4];
#pragma unroll
            for (int i=0;i<4;++i) af[i] = *(const bf16x8*)&As[ar_base + i*16*64 + ce];
#pragma unroll
            for (int j=0;j<4;++j) bf[j] = *(const bf16x8*)&Bs[br_base + j*16*64 + ce];
#pragma unroll
            for (int i=0;i<4;++i)
#pragma unroll
              for (int j=0;j<4;++j)
                acc[i][j] = __builtin_amdgcn_mfma_f32_16x16x32_bf16(af[i], bf[j], acc[i][j], 0,0,0);
        }
        __syncthreads();
    }

    const int mw = (w>>1)*64;
    const int nw = (w&1)*64;
    const int ccolb = ccol_stride*dir;

    const bool staged = (EPI==2) || (EPI==3) || (EPI==6) ||
                        (EPI==7 && n0 < 768);
    if (staged){
        bf16_t* Cs = smem;
#pragma unroll
        for (int i=0;i<4;++i){
#pragma unroll
            for (int reg=0; reg<4; ++reg){
                int rowl = mw + i*16 + q*4 + reg;
#pragma unroll
                for (int j=0;j<4;++j){
                    int coll = nw + j*16 + ln16;
                    float v = acc[i][j][reg];
                    if (EPI==3){
                        v += bias[n0 + coll];
                        v = 0.5f*v*(1.0f + erff(v*0.70710678118654752f));
                    } else if (EPI==7){
                        v = softplus_f(v + bias[n0 + coll]);
                    }
                    Cs[rowl*128 + coll] = (bf16_t)v;
                }
            }
        }
        __syncthreads();
        bf16_t* o = (bf16_t*)out1 + (long)dir*o1_stride;
        if (EPI==6 || EPI==7){
            // transposed-tiled store: X[((r>>3)*ldc + n)*8 + (r&7)]
#pragma unroll
            for (int c=0;c<8;++c){
                int chunk = tid + 256*c;        // 0..2047
                int nb  = chunk & 127;          // lane-consecutive n
                int tbl = chunk >> 7;           // 0..15 t-block within tile
                bf16x8 v;
#pragma unroll
                for (int u=0;u<8;++u) v[u] = Cs[(tbl*8+u)*128 + nb];
                long base = ((long)(m0/8 + tbl)*ldc + (n0 + nb))*8;
                *(bf16x8*)&o[base] = v;
            }
        } else {
#pragma unroll
            for (int c=0;c<8;++c){
                int chunk = tid + 256*c;        // 0..2047
                int rowl = chunk >> 4;
                int coll = (chunk & 15)*8;
                int r = m0 + rowl;
                *(int4*)&o[(long)r*ldc + ccolb + n0 + coll] = *(const int4*)&Cs[rowl*128 + coll];
            }
        }
    } else {
        // ---- scalar epilogue (EPI 4, or EPI 7 bc-tile) ----
#pragma unroll
        for (int i=0;i<4;++i){
#pragma unroll
            for (int reg=0; reg<4; ++reg){
                int r = m0 + mw + i*16 + q*4 + reg;
#pragma unroll
                for (int j=0;j<4;++j){
                    int col = n0 + nw + j*16 + ln16;
                    if (col >= N) continue;
                    float v = acc[i][j][reg];
                    if (EPI==4){
                        v += bias[col] + resid[(long)r*CC + col];
                        ((float*)out1)[(long)r*ldc + col] = v;
                    } else { // EPI==7 bc tile (col in [768, 800))
                        ((float*)out2 + (long)dir*o2_stride)[(long)r*32 + (col-768)] = v;
                    }
                }
            }
        }
    }
}

// ---------------- selective scan: tiled b128 loads, permuted y write --------
// Register-light fast path: ek[k]=e1^(k+1) from 5 live scalars + running
// group multiplier. PASS3 writes y at its FINAL (un-permuted) position
// (row sidx[jp] dir0 / sidx[LL-1-jp] dir1; uniform scalar index per row,
// write stays 512B-coalesced) so fuse1 reads sequential rows.
template<int PASS>
__global__ __launch_bounds__(256)
void scanp_k(const bf16_t* __restrict__ dtp, const bf16_t* __restrict__ xcp,
             const float* __restrict__ bcp, const bf16_t* __restrict__ xzp,
             const float* __restrict__ Al0, const float* __restrict__ Al1,
             const float* __restrict__ Dp0, const float* __restrict__ Dp1,
             float* __restrict__ Aprod, float* __restrict__ Hend,
             bf16_t* __restrict__ yout, const int* __restrict__ sidx)
{
    __shared__ __align__(16) float s_bc[LCH*32];   // 6144 B

    const int dir = blockIdx.y;
    int blk = blockIdx.x;
    const int dblk = blk % 3; int tmp = blk / 3;
    const int j = tmp % NCH; const int b = tmp / NCH;
    const int tid = threadIdx.x;
    const long tbase = (long)b*LL + (long)j*LCH;
    const long tb0 = tbase >> 3;
    const int d = dblk*256 + tid;

    const float* gbc = bcp + dir*S_BC + tbase*32;
    async_copy16(gbc + tid*4, s_bc + tid*4);
    if (tid < 128) async_copy16(gbc + (256+tid)*4, s_bc + (256+tid)*4);

    const float* Al = dir ? Al1 : Al0;
    float ac2[16]; bool fast = true;
#pragma unroll
    for (int k=0;k<16;++k){
        float a = -__expf(Al[d*DSTATE + k]);
        fast = fast && (fabsf(a + (float)(k+1)) < 1e-3f*(float)(k+1));
        ac2[k] = a * L2E;
    }

    const bf16_t* gdt = dtp + dir*S_DT + (tb0*768  + d)*8;
    const bf16_t* gxc = xcp + dir*S_XC + (tb0*768  + d)*8;
    const bf16_t* gz  = xzp + dir*S_XZ + (tb0*1536 + 768 + d)*8;
    bf16_t* gyb = yout + dir*S_YB + (long)b*LL*DINNER + d;

    const long o = dir*S_AP + ((long)(b*NCH + j)*DINNER + d)*DSTATE;

    float h[16];
    float dpv = 0.f;
    if (PASS==3){
#pragma unroll
        for (int g=0; g<4; ++g){
            f32x4 hv = *(const f32x4*)&Aprod[o + 4*g];
#pragma unroll
            for (int k=0;k<4;++k) h[g*4+k] = hv[k];
        }
        dpv = (dir ? Dp1 : Dp0)[d];
    } else {
#pragma unroll
        for (int k=0;k<16;++k) h[k] = 0.f;
    }
    float sdt = 0.f;

    __syncthreads();   // s_bc ready

#pragma unroll 1
    for (int cc=0; cc<LCH/8; ++cc){
        bf16x8 vdt = *(const bf16x8*)&gdt[(long)cc*6144];      // 768*8
        bf16x8 vxc = *(const bf16x8*)&gxc[(long)cc*6144];
        bf16x8 vz;
        if (PASS==3) vz = *(const bf16x8*)&gz[(long)cc*12288]; // 1536*8
#pragma unroll
        for (int u=0; u<8; ++u){
            const int t = cc*8 + u;
            float dt = (float)vdt[u];
            float xv = (float)vxc[u];
            float c = dt*xv;
            if (PASS==1) sdt += dt;
            const float* bcr = &s_bc[t*32];
            float p = 0.f;
            if (fast){
                float e1 = __builtin_amdgcn_exp2f(-L2E*dt);
                float e2 = e1*e1, e3 = e2*e1, e4 = e2*e2;
                float m = 1.0f;
#pragma unroll
                for (int g=0; g<4; ++g){
                    f32x4 Bv = *(const f32x4*)&bcr[g*4];
                    h[g*4+0] = (m*e1)*h[g*4+0] + c*Bv[0];
                    h[g*4+1] = (m*e2)*h[g*4+1] + c*Bv[1];
                    h[g*4+2] = (m*e3)*h[g*4+2] + c*Bv[2];
                    h[g*4+3] = (m*e4)*h[g*4+3] + c*Bv[3];
                    if (PASS==3){
                        f32x4 Cv = *(const f32x4*)&bcr[16 + g*4];
                        p += h[g*4+0]*Cv[0] + h[g*4+1]*Cv[1]
                           + h[g*4+2]*Cv[2] + h[g*4+3]*Cv[3];
                    }
                    m *= e4;
                }
            } else {
#pragma unroll
                for (int g=0; g<4; ++g){
                    f32x4 Bv = *(const f32x4*)&bcr[g*4];
#pragma unroll
                    for (int k=0;k<4;++k)
                        h[g*4+k] = __builtin_amdgcn_exp2f(dt*ac2[g*4+k])*h[g*4+k] + c*Bv[k];
                    if (PASS==3){
                        f32x4 Cv = *(const f32x4*)&bcr[16 + g*4];
                        p += h[g*4+0]*Cv[0] + h[g*4+1]*Cv[1]
                           + h[g*4+2]*Cv[2] + h[g*4+3]*Cv[3];
                    }
                }
            }
            if (PASS==3){
                float zv = (float)vz[u];
                int jp = j*LCH + t;
                int prow = dir ? sidx[LL-1-jp] : sidx[jp];
                gyb[(long)prow*DINNER] = (bf16_t)((p + dpv*xv) * silu_f(zv));
            }
        }
    }

    if (PASS==1){
        float e1s = __builtin_amdgcn_exp2f(-L2E*sdt);
        float e2s = e1s*e1s, e3s = e2s*e1s, e4s = e2s*e2s;
        float m = 1.0f;
#pragma unroll
        for (int g=0; g<4; ++g){
            f32x4 av, hv;
            if (fast){
                av[0]=m*e1s; av[1]=m*e2s; av[2]=m*e3s; av[3]=m*e4s;
                m *= e4s;
            } else {
#pragma unroll
                for (int k=0;k<4;++k) av[k] = __builtin_amdgcn_exp2f(sdt*ac2[g*4+k]);
            }
#pragma unroll
            for (int k=0;k<4;++k) hv[k] = h[g*4+k];
            *(f32x4*)&Aprod[o+4*g] = av;
            *(f32x4*)&Hend[o+4*g]  = hv;
        }
    }
}

// pass2: sequential combine (both dirs); carry-in written IN PLACE into Aprod
__global__ __launch_bounds__(256)
void scan2_k(float* __restrict__ Aprod, const float* __restrict__ Hend)
{
    int idx = blockIdx.x*256 + threadIdx.x;
    if (idx >= 2*BB*DINNER*DSTATE) return;
    int dir = idx / (BB*DINNER*DSTATE);
    int rem = idx - dir*(BB*DINNER*DSTATE);
    int b = rem / (DINNER*DSTATE);
    int ds = rem % (DINNER*DSTATE);
    long base = (long)dir*S_AP;
    float h = 0.f;
    for (int j=0;j<NCH;++j){
        long o = base + (long)(b*NCH+j)*DINNER*DSTATE + ds;
        float ap = Aprod[o];
        float he = Hend[o];
        Aprod[o] = h;
        h = ap*h + he;
    }
}

// ----------------------------------------------------------------------------
extern "C" void kernel_launch(void* const* d_in, const int* in_sizes, int n_in,
                              void* d_out, int out_size, void* d_ws, size_t ws_size,
                              hipStream_t stream)
{
    const float* x       = (const float*)d_in[0];
    const int*   sidx    = (const int*)  d_in[1];
    const float* norm_g  = (const float*)d_in[2];
    const float* norm_b  = (const float*)d_in[3];
    const float* fuse_w1 = (const float*)d_in[4];
    const float* fuse_b1 = (const float*)d_in[5];
    const float* fuse_w2 = (const float*)d_in[6];
    const float* fuse_b2 = (const float*)d_in[7];
    const float* f_in_w   = (const float*)d_in[8];
    const float* f_conv_w = (const float*)d_in[9];
    const float* f_conv_b = (const float*)d_in[10];
    const float* f_xproj  = (const float*)d_in[11];
    const float* f_dt_w   = (const float*)d_in[12];
    const float* f_dt_b   = (const float*)d_in[13];
    const float* f_A_log  = (const float*)d_in[14];
    const float* f_Dp     = (const float*)d_in[15];
    const float* f_out_w  = (const float*)d_in[16];
    const float* b_in_w   = (const float*)d_in[17];
    const float* b_conv_w = (const float*)d_in[18];
    const float* b_conv_b = (const float*)d_in[19];
    const float* b_xproj  = (const float*)d_in[20];
    const float* b_dt_w   = (const float*)d_in[21];
    const float* b_dt_b   = (const float*)d_in[22];
    const float* b_A_log  = (const float*)d_in[23];
    const float* b_Dp     = (const float*)d_in[24];
    const float* b_out_w  = (const float*)d_in[25];
    float* out = (float*)d_out;

    // ---- workspace layout (float units) ----
    float* ws    = (float*)d_ws;
    bf16_t* xn   = (bf16_t*)ws;                        // 7,077,888 bf16 (PERMUTED; reused as xcR dir0)
    bf16_t* xz   = (bf16_t*)(ws + 3538944);            // 2 x 14,155,776 bf16 (TILED 1536)
    bf16_t* xc   = (bf16_t*)(ws + 17694720);           // 2 x 7,077,888 bf16  (TILED 768)
    bf16_t* dtb  = (bf16_t*)(ws + 24772608);           // 2 x 7,077,888 bf16  (TILED 768)
    float* bc    = ws + 31850496;                      // 2 x 294,912 fl
    bf16_t* yb   = (bf16_t*)(ws + 32440320);           // 2 x 7,077,888 bf16  (PERMUTED [t][d])
    bf16_t* h1   = (bf16_t*)(ws + 39518208);           // 7,077,888 bf16 (first: xcR dir1)
    float* Aprod = ws + 43057152;                      // 2 x 2,359,296 fl
    float* Hend  = ws + 47775744;                      // 2 x 2,359,296 fl
    bf16_t* wbf  = (bf16_t*)(ws + 52494336);           // 7,716,864 bf16

    bf16_t* w_fin    = wbf + 0;
    bf16_t* w_bin    = wbf + 1179648;
    bf16_t* w_1      = wbf + 2359296;   // 768 x 1536
    bf16_t* w_2      = wbf + 3538944;   // 768 x 768
    bf16_t* w_fcombo = wbf + 4128768;   // 800 x 768
    bf16_t* w_bcombo = wbf + 4743168;   // 800 x 768
    bf16_t* foutT    = wbf + 5357568;   // 768 x 768 (f_out_w^T)
    bf16_t* boutT    = wbf + 5947392;   // 768 x 768
    bf16_t* Ccat     = wbf + 6537216;   // 768 x 1536 ([W1a@fout | W1b@bout])

    bf16_t* xcR0 = xn;                  // row-major xc, dir 0 (xn dead after in-proj)
    bf16_t* xcR1 = h1;                  // row-major xc, dir 1 (h1 written later)

    // ---- merged preprocessing: ln + wconv + transp + combo (1 launch) ----
    prep_k<<<28224, 256, 0, stream>>>(
        x, norm_g, norm_b, sidx, xn,
        f_in_w, b_in_w, fuse_w1, fuse_w2, f_xproj + 48*768, b_xproj + 48*768, wbf,
        f_out_w, b_out_w, foutT, boutT,
        f_dt_w, f_xproj, b_dt_w, b_xproj, w_fcombo, w_bcombo);
    // Ccat: dir0: Cf[n][d] = sum_c W1[n][c]*foutT[d][c]; dir1 +768 col offset
    gemm4_k<0,0,2><<<dim3(6,6,2), 256, 0, stream>>>(
        w_1, 768, 1536, foutT, boutT, 768, 768,
        Ccat, 0, nullptr, 0, 1536, 768, nullptr, nullptr, nullptr);

    // ---- in-projection (both dirs, sequential reads of permuted xn) ----
    gemm4_k<6,0,6><<<dim3(72,12,2), 256, 0, stream>>>(
        xn, 0, CC, w_fin, w_bin, 1536, 768,
        xz, S_XZ, nullptr, 0, 1536, 0, nullptr, nullptr, nullptr);
    // ---- depthwise conv (channel-major tiled; writes tiled + row-major) ----
    conv_k<<<dim3(1728, 2), 256, 0, stream>>>(
        xz, f_conv_w, b_conv_w, f_conv_b, b_conv_b, xc, xcR0, xcR1);
    // ---- combo projection: softplus(dt) TILED + B/C (both dirs) ----
    gemm4_k<0,0,7><<<dim3(72,7,2), 256, 0, stream>>>(
        xcR0, S_XCR, DINNER, w_fcombo, w_bcombo, 800, 768,
        dtb, S_DT, bc, S_BC, 768, 0, f_dt_b, b_dt_b, nullptr);
    // ---- selective scan (both dirs, tiled b128 loads, permuted y write) ----
    scanp_k<1><<<dim3(BB*NCH*3,2), 256, 0, stream>>>(
        dtb, xc, bc, xz, f_A_log, b_A_log, f_Dp, b_Dp, Aprod, Hend, yb, sidx);
    scan2_k<<<384, 256, 0, stream>>>(Aprod, Hend);
    scanp_k<3><<<dim3(BB*NCH*3,2), 256, 0, stream>>>(
        dtb, xc, bc, xz, f_A_log, b_A_log, f_Dp, b_Dp, Aprod, Hend, yb, sidx);
    // ---- fused out-proj + fuse1 (sequential dual-phase reads of permuted yb) ----
    gemm4_k<7,0,3><<<dim3(72,6,1), 256, 0, stream>>>(
        yb, S_YB, DINNER, Ccat, Ccat, 768, 1536,
        h1, 0, nullptr, 0, 768, 0, fuse_b1, fuse_b1, nullptr);
    // ---- fuse2 + residual ----
    gemm4_k<0,0,4><<<dim3(72,6,1), 256, 0, stream>>>(
        h1, 0, DINNER, w_2, w_2, 768, 768,
        out, 0, nullptr, 0, 768, 0, fuse_b2, fuse_b2, x);
}

// Round 12
// 448.260 us; speedup vs baseline: 1.2561x; 1.0536x over previous
//
#include <hip/hip_runtime.h>
#include <hip/hip_bf16.h>
#include <cmath>

#define BB 4
#define LL 2304
#define CC 768
#define DSTATE 16
#define DINNER 768
#define DTRANK 48
#define MTOK (BB*LL)          // 9216
#define NCH 48
#define LCH (LL/NCH)          // 48

// per-direction strides (element units)
#define S_XZ   14155776L
#define S_XC   7077888L
#define S_DT   7077888L
#define S_BC   294912L
#define S_YB   7077888L
#define S_AP   2359296L
#define S_XCR  79036416L      // gap between xcR dir0 (xn slot) and dir1 (h1 slot)

#define L2E 1.4426950408889634f

typedef __bf16 bf16_t;
typedef __bf16 bf16x8 __attribute__((ext_vector_type(8)));
typedef float  f32x4  __attribute__((ext_vector_type(4)));

__device__ __forceinline__ float silu_f(float v){ return v / (1.0f + __expf(-v)); }
__device__ __forceinline__ float softplus_f(float v){
    return fmaxf(v,0.f) + __logf(1.0f + __expf(-fabsf(v)));
}

typedef __attribute__((address_space(3))) void  lds_vt;
typedef __attribute__((address_space(1))) void  gbl_vt;
__device__ __forceinline__ void async_copy16(const void* g, void* l){
    __builtin_amdgcn_global_load_lds((const gbl_vt*)g, (lds_vt*)l, 16, 0, 0);
}

// TILED time-contiguous layout for scan operands:
//   X[tb][Ndim][8], element (r,n) at ((r>>3)*Ndim + n)*8 + (r&7).
// PRE-PERMUTED buffers: producers place rows in scan order once, so the
// downstream GEMMs read SEQUENTIAL rows.

// ---------------- merged preprocessing kernel -------------------------------
// Block ranges: [0,9216) ln | [9216,25536) wconv | [25536,26688) transp |
// [26688,28224) combo.  ln gather-reads x[bo+sidx[p]] -> writes xn[bo+p]
// sequentially.
__global__ __launch_bounds__(256)
void prep_k(const float* __restrict__ x, const float* __restrict__ g,
            const float* __restrict__ bta, const int* __restrict__ sidx,
            bf16_t* __restrict__ xn,
            const float* __restrict__ a0, const float* __restrict__ a1,
            const float* __restrict__ a2, const float* __restrict__ a3,
            const float* __restrict__ a4, const float* __restrict__ a5,
            bf16_t* __restrict__ wdst,
            const float* __restrict__ t0s, const float* __restrict__ t1s,
            bf16_t* __restrict__ t0d, bf16_t* __restrict__ t1d,
            const float* __restrict__ fdtw, const float* __restrict__ fxp,
            const float* __restrict__ bdtw, const float* __restrict__ bxp,
            bf16_t* __restrict__ fcombo, bf16_t* __restrict__ bcombo)
{
    const int bid = blockIdx.x;
    const int tid = threadIdx.x;

    if (bid < 9216){
        // ---- LayerNorm, permuted via gather-read, sequential write ----
        int row = bid;
        int p = row % LL;
        long srow = (long)(row - p) + sidx[p];
        const float* xr = x + srow*CC;
        float v[3];
#pragma unroll
        for (int r=0;r<3;++r) v[r] = xr[tid + 256*r];
        float s  = v[0]+v[1]+v[2];
        float s2 = v[0]*v[0]+v[1]*v[1]+v[2]*v[2];
        __shared__ float red[8];
        for (int o=32;o;o>>=1){ s += __shfl_down(s,o); s2 += __shfl_down(s2,o); }
        int wv = tid>>6, ln = tid&63;
        if (ln==0){ red[wv]=s; red[4+wv]=s2; }
        __syncthreads();
        if (tid==0){
            red[0] = red[0]+red[1]+red[2]+red[3];
            red[4] = red[4]+red[5]+red[6]+red[7];
        }
        __syncthreads();
        float mu  = red[0]*(1.0f/CC);
        float var = red[4]*(1.0f/CC) - mu*mu;
        float rstd = rsqrtf(var + 1e-6f);
#pragma unroll
        for (int r=0;r<3;++r){
            int c = tid + 256*r;
            xn[(long)row*CC + c] = (bf16_t)((v[r]-mu)*rstd*g[c] + bta[c]);
        }
    } else if (bid < 25536){
        // ---- weight fp32 -> bf16 conversion ----
        const int cum[7]  = {0,1179648,2359296,3538944,4128768,4153344,4177920};
        const int dofs[6] = {0,1179648,2359296,3538944,4718592,5332992};
        const float* srcs[6] = {a0,a1,a2,a3,a4,a5};
        int idx = (bid-9216)*256 + tid;
        if (idx >= 4177920) return;
        int seg = 0;
        while (idx >= cum[seg+1]) ++seg;
        wdst[dofs[seg] + idx - cum[seg]] = (bf16_t)srcs[seg][idx - cum[seg]];
    } else if (bid < 26688){
        // ---- transpose+convert 768x768 fp32 -> bf16 (dst = src^T) ----
        __shared__ float tile[32][33];
        int tix = bid - 25536;              // 0..1151
        int bx = tix % 24, by = (tix/24) % 24, bz = tix / 576;
        const float* src = bz ? t1s : t0s;
        bf16_t* dst = bz ? t1d : t0d;
        int c0 = by*32, d0c = bx*32;
        int tx = tid & 31, ty = tid >> 5;   // ty 0..7
#pragma unroll
        for (int r=0;r<4;++r)
            tile[ty+8*r][tx] = src[(long)(c0+ty+8*r)*768 + d0c+tx];
        __syncthreads();
#pragma unroll
        for (int r=0;r<4;++r)
            dst[(long)(d0c+ty+8*r)*768 + c0+tx] = (bf16_t)tile[tx][ty+8*r];
    } else {
        // ---- combo weight: dst[n*768+k] = sum_r dtw[n*48+r]*xproj[r*768+k] --
        __shared__ float row[48];
        int cidx = bid - 26688;             // 0..1535
        int n = cidx & 767;
        const float* dtw = (cidx < 768) ? fdtw : bdtw;
        const float* xproj = (cidx < 768) ? fxp : bxp;
        bf16_t* dst = (cidx < 768) ? fcombo : bcombo;
        if (tid < 48) row[tid] = dtw[n*48 + tid];
        __syncthreads();
#pragma unroll
        for (int kk=0; kk<3; ++kk){
            int k = tid + 256*kk;
            float s = 0.f;
#pragma unroll 8
            for (int r=0; r<48; ++r) s += row[r]*xproj[r*768 + k];
            dst[n*768 + k] = (bf16_t)s;
        }
    }
}

// ---------------- depthwise causal conv (k=4) + silu, tiled layout ----------
__global__ __launch_bounds__(256)
void conv_k(const bf16_t* __restrict__ xzT, const float* __restrict__ cw0,
            const float* __restrict__ cw1, const float* __restrict__ cb0,
            const float* __restrict__ cb1, bf16_t* __restrict__ xcT,
            bf16_t* __restrict__ xcR0, bf16_t* __restrict__ xcR1)
{
    const int dir = blockIdx.y;
    const bf16_t* src = xzT + (long)dir*S_XZ;
    bf16_t* dstT = xcT + (long)dir*S_XC;
    bf16_t* dstR = dir ? xcR1 : xcR0;
    const float* cw = dir ? cw1 : cw0;
    const float* cb = dir ? cb1 : cb0;
    int idx = blockIdx.x*256 + threadIdx.x;     // 768 * 576
    int d = idx % 768;                          // consecutive lanes -> consecutive d
    int chunk = idx / 768;                      // 0..575  (16-t chunks)
    int tb = chunk*2;
    int r0 = chunk*16;

    bf16x8 c0 = *(const bf16x8*)&src[((long)tb*1536 + d)*8];
    bf16x8 c1 = *(const bf16x8*)&src[((long)(tb+1)*1536 + d)*8];
    float xm3, xm2, xm1;
    if (r0 % LL){
        bf16x8 pv = *(const bf16x8*)&src[((long)(tb-1)*1536 + d)*8];
        xm3=(float)pv[5]; xm2=(float)pv[6]; xm1=(float)pv[7];
    } else { xm3=0.f; xm2=0.f; xm1=0.f; }

    float4 w = *(const float4*)&cw[d*4];
    float bz = cb[d];

    float xx[16];
#pragma unroll
    for (int u=0;u<8;++u){ xx[u]=(float)c0[u]; xx[8+u]=(float)c1[u]; }
    bf16x8 o0, o1;
#pragma unroll
    for (int u=0;u<16;++u){
        float cur = xx[u];
        float acc = bz + w.x*xm3 + w.y*xm2 + w.z*xm1 + w.w*cur;
        float r = silu_f(acc);
        if (u < 8) o0[u] = (bf16_t)r; else o1[u-8] = (bf16_t)r;
        xm3 = xm2; xm2 = xm1; xm1 = cur;
    }
    *(bf16x8*)&dstT[((long)tb*768 + d)*8]     = o0;
    *(bf16x8*)&dstT[((long)(tb+1)*768 + d)*8] = o1;
#pragma unroll
    for (int u=0;u<8;++u){
        dstR[(long)(r0+u)*DINNER + d]   = o0[u];
        dstR[(long)(r0+8+u)*DINNER + d] = o1[u];
    }
}

// ---------------- GEMM4: LDS-staged MFMA GEMM, 128x128 tile, BK=64 ----------
// GATHER: 0 none | 6 permuted-input: dir0 sequential rows, dir1 descending
//         rows (reverse view of the same pre-permuted buffer) |
//         7 sequential dual-phase A (k<768: A row r; k>=768: A+a_stride row r)
// EPI: 2 store bf16 (staged wide) | 3 gelu+bias->bf16 (staged) |
//      4 bias+resid->f32 STAGED float4 (R12) | 6 bf16 TRANSPOSED-TILED |
//      7 softplus TRANSPOSED-TILED + bc scalar
template<int GATHER, int SCATTER, int EPI>
__global__ __launch_bounds__(256)
void gemm4_k(const bf16_t* __restrict__ A, long a_stride, int lda,
             const bf16_t* __restrict__ W0, const bf16_t* __restrict__ W1,
             int N, int K,
             void* __restrict__ out1, long o1_stride,
             void* __restrict__ out2, long o2_stride,
             int ldc, int ccol_stride,
             const float* __restrict__ bias0, const float* __restrict__ bias1,
             const float* __restrict__ resid)
{
    __shared__ __align__(16) bf16_t smem[2*128*64];   // As | Bs ; reused as Cs
    bf16_t* As = smem;
    bf16_t* Bs = smem + 128*64;

    const int tid  = threadIdx.x;
    const int lane = tid & 63;
    const int w    = tid >> 6;
    const int ln16 = lane & 15;
    const int q    = lane >> 4;
    const int dir  = blockIdx.z;

    const bf16_t* Ad = A + (long)dir*a_stride;
    const bf16_t* W  = dir ? W1 : W0;
    const float* bias = dir ? bias1 : bias0;

    const int m0 = blockIdx.x*128;
    const int n0 = blockIdx.y*128;

    const int srow = lane >> 3;
    const int csrc = (lane & 7) ^ srow;
    const bf16_t* gA[4]; const bf16_t* gA1[4]; const bf16_t* gB[4];
#pragma unroll
    for (int inst=0; inst<4; ++inst){
        int row = w*32 + inst*8 + srow;
        int r = m0 + row;
        if (GATHER == 7){
            gA[inst]  = A + (long)r*lda + csrc*8;
            gA1[inst] = A + a_stride + (long)r*lda + csrc*8;
        } else {
            int sr = r;
            if (GATHER == 6 && dir){
                int t = r % LL;
                sr = r - t + (LL-1-t);
            }
            gA[inst] = Ad + (long)sr*lda + csrc*8;
        }
        int n = n0 + row; if (n >= N) n = N-1;
        gB[inst] = W + (long)n*K + csrc*8;
    }

    f32x4 acc[4][4];
#pragma unroll
    for (int i=0;i<4;++i)
#pragma unroll
      for (int j=0;j<4;++j) acc[i][j] = (f32x4){0.f,0.f,0.f,0.f};

    const int e = ln16 & 7;
    const int ar_base = ((w>>1)*64 + ln16)*64;
    const int br_base = ((w&1)*64 + ln16)*64;

    for (int k0 = 0; k0 < K; k0 += 64){
#pragma unroll
        for (int inst=0; inst<4; ++inst){
            bf16_t* la = As + (w*256 + inst*64)*8;
            bf16_t* lb = Bs + (w*256 + inst*64)*8;
            const bf16_t* asrc;
            if (GATHER == 7)
                asrc = (k0 >= 768) ? (gA1[inst] + (k0 - 768)) : (gA[inst] + k0);
            else
                asrc = gA[inst] + k0;
            async_copy16(asrc, la);
            async_copy16(gB[inst] + k0, lb);
        }
        __syncthreads();
#pragma unroll
        for (int kk=0; kk<2; ++kk){
            const int ce = (((kk<<2)|q) ^ e)*8;
            bf16x8 af[4], bf[4];
#pragma unroll
            for (int i=0;i<4;++i) af[i] = *(const bf16x8*)&As[ar_base + i*16*64 + ce];
#pragma unroll
            for (int j=0;j<4;++j) bf[j] = *(const bf16x8*)&Bs[br_base + j*16*64 + ce];
#pragma unroll
            for (int i=0;i<4;++i)
#pragma unroll
              for (int j=0;j<4;++j)
                acc[i][j] = __builtin_amdgcn_mfma_f32_16x16x32_bf16(af[i], bf[j], acc[i][j], 0,0,0);
        }
        __syncthreads();
    }

    const int mw = (w>>1)*64;
    const int nw = (w&1)*64;
    const int ccolb = ccol_stride*dir;

    const bool staged = (EPI==2) || (EPI==3) || (EPI==6) ||
                        (EPI==7 && n0 < 768);
    if (staged){
        bf16_t* Cs = smem;
#pragma unroll
        for (int i=0;i<4;++i){
#pragma unroll
            for (int reg=0; reg<4; ++reg){
                int rowl = mw + i*16 + q*4 + reg;
#pragma unroll
                for (int j=0;j<4;++j){
                    int coll = nw + j*16 + ln16;
                    float v = acc[i][j][reg];
                    if (EPI==3){
                        v += bias[n0 + coll];
                        v = 0.5f*v*(1.0f + erff(v*0.70710678118654752f));
                    } else if (EPI==7){
                        v = softplus_f(v + bias[n0 + coll]);
                    }
                    Cs[rowl*128 + coll] = (bf16_t)v;
                }
            }
        }
        __syncthreads();
        bf16_t* o = (bf16_t*)out1 + (long)dir*o1_stride;
        if (EPI==6 || EPI==7){
            // transposed-tiled store: X[((r>>3)*ldc + n)*8 + (r&7)]
#pragma unroll
            for (int c=0;c<8;++c){
                int chunk = tid + 256*c;        // 0..2047
                int nb  = chunk & 127;          // lane-consecutive n
                int tbl = chunk >> 7;           // 0..15 t-block within tile
                bf16x8 v;
#pragma unroll
                for (int u=0;u<8;++u) v[u] = Cs[(tbl*8+u)*128 + nb];
                long base = ((long)(m0/8 + tbl)*ldc + (n0 + nb))*8;
                *(bf16x8*)&o[base] = v;
            }
        } else {
#pragma unroll
            for (int c=0;c<8;++c){
                int chunk = tid + 256*c;        // 0..2047
                int rowl = chunk >> 4;
                int coll = (chunk & 15)*8;
                int r = m0 + rowl;
                *(int4*)&o[(long)r*ldc + ccolb + n0 + coll] = *(const int4*)&Cs[rowl*128 + coll];
            }
        }
    } else if (EPI==4){
        // ---- R12: staged f32 epilogue, two 64x128 halves, float4 I/O ----
        // Stage writes: rows differ by 4 (512 words = 0 mod 32) -> 4-way LDS
        // write conflict, ~1.58x on one pass (negligible). Reads + global
        // traffic fully coalesced float4 (replaces 64x 64B-segment scalar
        // stores + loads per thread).
        float* Csf = (float*)smem;              // 64 x 128 f32 = 32KB
        float* o1 = (float*)out1;
#pragma unroll
        for (int hh=0; hh<2; ++hh){
            if ((w>>1) == hh){
#pragma unroll
                for (int i=0;i<4;++i){
#pragma unroll
                    for (int reg=0; reg<4; ++reg){
                        int rowl = i*16 + q*4 + reg;          // 0..63 in half
#pragma unroll
                        for (int j=0;j<4;++j){
                            int coll = nw + j*16 + ln16;
                            Csf[rowl*128 + coll] = acc[i][j][reg] + bias[n0 + coll];
                        }
                    }
                }
            }
            __syncthreads();
#pragma unroll
            for (int c=0;c<8;++c){
                int chunk = tid + 256*c;        // 0..2047
                int rowl = chunk >> 5;          // 0..63
                int c4   = chunk & 31;          // float4 block
                int r = m0 + hh*64 + rowl;
                int col = n0 + c4*4;
                float4 v = *(const float4*)&Csf[rowl*128 + c4*4];
                float4 rs = *(const float4*)&resid[(long)r*CC + col];
                v.x += rs.x; v.y += rs.y; v.z += rs.z; v.w += rs.w;
                *(float4*)&o1[(long)r*ldc + col] = v;
            }
            __syncthreads();
        }
    } else {
        // ---- scalar epilogue (EPI 7 bc-tile) ----
#pragma unroll
        for (int i=0;i<4;++i){
#pragma unroll
            for (int reg=0; reg<4; ++reg){
                int r = m0 + mw + i*16 + q*4 + reg;
#pragma unroll
                for (int j=0;j<4;++j){
                    int col = n0 + nw + j*16 + ln16;
                    if (col >= N) continue;
                    float v = acc[i][j][reg];
                    ((float*)out2 + (long)dir*o2_stride)[(long)r*32 + (col-768)] = v;
                }
            }
        }
    }
}

// ---------------- selective scan: tiled b128 loads, permuted y write --------
// Register-light fast path: ek[k]=e1^(k+1) from 5 live scalars + running
// group multiplier. PASS3 writes y at its FINAL (un-permuted) position so
// fuse1 reads sequential rows.
template<int PASS>
__global__ __launch_bounds__(256)
void scanp_k(const bf16_t* __restrict__ dtp, const bf16_t* __restrict__ xcp,
             const float* __restrict__ bcp, const bf16_t* __restrict__ xzp,
             const float* __restrict__ Al0, const float* __restrict__ Al1,
             const float* __restrict__ Dp0, const float* __restrict__ Dp1,
             float* __restrict__ Aprod, float* __restrict__ Hend,
             bf16_t* __restrict__ yout, const int* __restrict__ sidx)
{
    __shared__ __align__(16) float s_bc[LCH*32];   // 6144 B

    const int dir = blockIdx.y;
    int blk = blockIdx.x;
    const int dblk = blk % 3; int tmp = blk / 3;
    const int j = tmp % NCH; const int b = tmp / NCH;
    const int tid = threadIdx.x;
    const long tbase = (long)b*LL + (long)j*LCH;
    const long tb0 = tbase >> 3;
    const int d = dblk*256 + tid;

    const float* gbc = bcp + dir*S_BC + tbase*32;
    async_copy16(gbc + tid*4, s_bc + tid*4);
    if (tid < 128) async_copy16(gbc + (256+tid)*4, s_bc + (256+tid)*4);

    const float* Al = dir ? Al1 : Al0;
    float ac2[16]; bool fast = true;
#pragma unroll
    for (int k=0;k<16;++k){
        float a = -__expf(Al[d*DSTATE + k]);
        fast = fast && (fabsf(a + (float)(k+1)) < 1e-3f*(float)(k+1));
        ac2[k] = a * L2E;
    }

    const bf16_t* gdt = dtp + dir*S_DT + (tb0*768  + d)*8;
    const bf16_t* gxc = xcp + dir*S_XC + (tb0*768  + d)*8;
    const bf16_t* gz  = xzp + dir*S_XZ + (tb0*1536 + 768 + d)*8;
    bf16_t* gyb = yout + dir*S_YB + (long)b*LL*DINNER + d;

    const long o = dir*S_AP + ((long)(b*NCH + j)*DINNER + d)*DSTATE;

    float h[16];
    float dpv = 0.f;
    if (PASS==3){
#pragma unroll
        for (int g=0; g<4; ++g){
            f32x4 hv = *(const f32x4*)&Aprod[o + 4*g];
#pragma unroll
            for (int k=0;k<4;++k) h[g*4+k] = hv[k];
        }
        dpv = (dir ? Dp1 : Dp0)[d];
    } else {
#pragma unroll
        for (int k=0;k<16;++k) h[k] = 0.f;
    }
    float sdt = 0.f;

    __syncthreads();   // s_bc ready

#pragma unroll 1
    for (int cc=0; cc<LCH/8; ++cc){
        bf16x8 vdt = *(const bf16x8*)&gdt[(long)cc*6144];      // 768*8
        bf16x8 vxc = *(const bf16x8*)&gxc[(long)cc*6144];
        bf16x8 vz;
        if (PASS==3) vz = *(const bf16x8*)&gz[(long)cc*12288]; // 1536*8
#pragma unroll
        for (int u=0; u<8; ++u){
            const int t = cc*8 + u;
            float dt = (float)vdt[u];
            float xv = (float)vxc[u];
            float c = dt*xv;
            if (PASS==1) sdt += dt;
            const float* bcr = &s_bc[t*32];
            float p = 0.f;
            if (fast){
                float e1 = __builtin_amdgcn_exp2f(-L2E*dt);
                float e2 = e1*e1, e3 = e2*e1, e4 = e2*e2;
                float m = 1.0f;
#pragma unroll
                for (int g=0; g<4; ++g){
                    f32x4 Bv = *(const f32x4*)&bcr[g*4];
                    h[g*4+0] = (m*e1)*h[g*4+0] + c*Bv[0];
                    h[g*4+1] = (m*e2)*h[g*4+1] + c*Bv[1];
                    h[g*4+2] = (m*e3)*h[g*4+2] + c*Bv[2];
                    h[g*4+3] = (m*e4)*h[g*4+3] + c*Bv[3];
                    if (PASS==3){
                        f32x4 Cv = *(const f32x4*)&bcr[16 + g*4];
                        p += h[g*4+0]*Cv[0] + h[g*4+1]*Cv[1]
                           + h[g*4+2]*Cv[2] + h[g*4+3]*Cv[3];
                    }
                    m *= e4;
                }
            } else {
#pragma unroll
                for (int g=0; g<4; ++g){
                    f32x4 Bv = *(const f32x4*)&bcr[g*4];
#pragma unroll
                    for (int k=0;k<4;++k)
                        h[g*4+k] = __builtin_amdgcn_exp2f(dt*ac2[g*4+k])*h[g*4+k] + c*Bv[k];
                    if (PASS==3){
                        f32x4 Cv = *(const f32x4*)&bcr[16 + g*4];
                        p += h[g*4+0]*Cv[0] + h[g*4+1]*Cv[1]
                           + h[g*4+2]*Cv[2] + h[g*4+3]*Cv[3];
                    }
                }
            }
            if (PASS==3){
                float zv = (float)vz[u];
                int jp = j*LCH + t;
                int prow = dir ? sidx[LL-1-jp] : sidx[jp];
                gyb[(long)prow*DINNER] = (bf16_t)((p + dpv*xv) * silu_f(zv));
            }
        }
    }

    if (PASS==1){
        float e1s = __builtin_amdgcn_exp2f(-L2E*sdt);
        float e2s = e1s*e1s, e3s = e2s*e1s, e4s = e2s*e2s;
        float m = 1.0f;
#pragma unroll
        for (int g=0; g<4; ++g){
            f32x4 av, hv;
            if (fast){
                av[0]=m*e1s; av[1]=m*e2s; av[2]=m*e3s; av[3]=m*e4s;
                m *= e4s;
            } else {
#pragma unroll
                for (int k=0;k<4;++k) av[k] = __builtin_amdgcn_exp2f(sdt*ac2[g*4+k]);
            }
#pragma unroll
            for (int k=0;k<4;++k) hv[k] = h[g*4+k];
            *(f32x4*)&Aprod[o+4*g] = av;
            *(f32x4*)&Hend[o+4*g]  = hv;
        }
    }
}

// pass2: sequential combine (both dirs); carry-in written IN PLACE into Aprod.
// R12: unroll 8 so the (address-independent) loads batch 16-deep instead of
// one ~500-cycle HBM latency per serial iteration.
__global__ __launch_bounds__(256)
void scan2_k(float* __restrict__ Aprod, const float* __restrict__ Hend)
{
    int idx = blockIdx.x*256 + threadIdx.x;
    if (idx >= 2*BB*DINNER*DSTATE) return;
    int dir = idx / (BB*DINNER*DSTATE);
    int rem = idx - dir*(BB*DINNER*DSTATE);
    int b = rem / (DINNER*DSTATE);
    int ds = rem % (DINNER*DSTATE);
    long base = (long)dir*S_AP;
    float h = 0.f;
#pragma unroll 8
    for (int j=0;j<NCH;++j){
        long o = base + (long)(b*NCH+j)*DINNER*DSTATE + ds;
        float ap = Aprod[o];
        float he = Hend[o];
        Aprod[o] = h;
        h = ap*h + he;
    }
}

// ----------------------------------------------------------------------------
extern "C" void kernel_launch(void* const* d_in, const int* in_sizes, int n_in,
                              void* d_out, int out_size, void* d_ws, size_t ws_size,
                              hipStream_t stream)
{
    const float* x       = (const float*)d_in[0];
    const int*   sidx    = (const int*)  d_in[1];
    const float* norm_g  = (const float*)d_in[2];
    const float* norm_b  = (const float*)d_in[3];
    const float* fuse_w1 = (const float*)d_in[4];
    const float* fuse_b1 = (const float*)d_in[5];
    const float* fuse_w2 = (const float*)d_in[6];
    const float* fuse_b2 = (const float*)d_in[7];
    const float* f_in_w   = (const float*)d_in[8];
    const float* f_conv_w = (const float*)d_in[9];
    const float* f_conv_b = (const float*)d_in[10];
    const float* f_xproj  = (const float*)d_in[11];
    const float* f_dt_w   = (const float*)d_in[12];
    const float* f_dt_b   = (const float*)d_in[13];
    const float* f_A_log  = (const float*)d_in[14];
    const float* f_Dp     = (const float*)d_in[15];
    const float* f_out_w  = (const float*)d_in[16];
    const float* b_in_w   = (const float*)d_in[17];
    const float* b_conv_w = (const float*)d_in[18];
    const float* b_conv_b = (const float*)d_in[19];
    const float* b_xproj  = (const float*)d_in[20];
    const float* b_dt_w   = (const float*)d_in[21];
    const float* b_dt_b   = (const float*)d_in[22];
    const float* b_A_log  = (const float*)d_in[23];
    const float* b_Dp     = (const float*)d_in[24];
    const float* b_out_w  = (const float*)d_in[25];
    float* out = (float*)d_out;

    // ---- workspace layout (float units) ----
    float* ws    = (float*)d_ws;
    bf16_t* xn   = (bf16_t*)ws;                        // 7,077,888 bf16 (PERMUTED; reused as xcR dir0)
    bf16_t* xz   = (bf16_t*)(ws + 3538944);            // 2 x 14,155,776 bf16 (TILED 1536)
    bf16_t* xc   = (bf16_t*)(ws + 17694720);           // 2 x 7,077,888 bf16  (TILED 768)
    bf16_t* dtb  = (bf16_t*)(ws + 24772608);           // 2 x 7,077,888 bf16  (TILED 768)
    float* bc    = ws + 31850496;                      // 2 x 294,912 fl
    bf16_t* yb   = (bf16_t*)(ws + 32440320);           // 2 x 7,077,888 bf16  (PERMUTED [t][d])
    bf16_t* h1   = (bf16_t*)(ws + 39518208);           // 7,077,888 bf16 (first: xcR dir1)
    float* Aprod = ws + 43057152;                      // 2 x 2,359,296 fl
    float* Hend  = ws + 47775744;                      // 2 x 2,359,296 fl
    bf16_t* wbf  = (bf16_t*)(ws + 52494336);           // 7,716,864 bf16

    bf16_t* w_fin    = wbf + 0;
    bf16_t* w_bin    = wbf + 1179648;
    bf16_t* w_1      = wbf + 2359296;   // 768 x 1536
    bf16_t* w_2      = wbf + 3538944;   // 768 x 768
    bf16_t* w_fcombo = wbf + 4128768;   // 800 x 768
    bf16_t* w_bcombo = wbf + 4743168;   // 800 x 768
    bf16_t* foutT    = wbf + 5357568;   // 768 x 768 (f_out_w^T)
    bf16_t* boutT    = wbf + 5947392;   // 768 x 768
    bf16_t* Ccat     = wbf + 6537216;   // 768 x 1536 ([W1a@fout | W1b@bout])

    bf16_t* xcR0 = xn;                  // row-major xc, dir 0 (xn dead after in-proj)
    bf16_t* xcR1 = h1;                  // row-major xc, dir 1 (h1 written later)

    // ---- merged preprocessing: ln + wconv + transp + combo (1 launch) ----
    prep_k<<<28224, 256, 0, stream>>>(
        x, norm_g, norm_b, sidx, xn,
        f_in_w, b_in_w, fuse_w1, fuse_w2, f_xproj + 48*768, b_xproj + 48*768, wbf,
        f_out_w, b_out_w, foutT, boutT,
        f_dt_w, f_xproj, b_dt_w, b_xproj, w_fcombo, w_bcombo);
    // Ccat: dir0: Cf[n][d] = sum_c W1[n][c]*foutT[d][c]; dir1 +768 col offset
    gemm4_k<0,0,2><<<dim3(6,6,2), 256, 0, stream>>>(
        w_1, 768, 1536, foutT, boutT, 768, 768,
        Ccat, 0, nullptr, 0, 1536, 768, nullptr, nullptr, nullptr);

    // ---- in-projection (both dirs, sequential reads of permuted xn) ----
    gemm4_k<6,0,6><<<dim3(72,12,2), 256, 0, stream>>>(
        xn, 0, CC, w_fin, w_bin, 1536, 768,
        xz, S_XZ, nullptr, 0, 1536, 0, nullptr, nullptr, nullptr);
    // ---- depthwise conv (channel-major tiled; writes tiled + row-major) ----
    conv_k<<<dim3(1728, 2), 256, 0, stream>>>(
        xz, f_conv_w, b_conv_w, f_conv_b, b_conv_b, xc, xcR0, xcR1);
    // ---- combo projection: softplus(dt) TILED + B/C (both dirs) ----
    gemm4_k<0,0,7><<<dim3(72,7,2), 256, 0, stream>>>(
        xcR0, S_XCR, DINNER, w_fcombo, w_bcombo, 800, 768,
        dtb, S_DT, bc, S_BC, 768, 0, f_dt_b, b_dt_b, nullptr);
    // ---- selective scan (both dirs, tiled b128 loads, permuted y write) ----
    scanp_k<1><<<dim3(BB*NCH*3,2), 256, 0, stream>>>(
        dtb, xc, bc, xz, f_A_log, b_A_log, f_Dp, b_Dp, Aprod, Hend, yb, sidx);
    scan2_k<<<384, 256, 0, stream>>>(Aprod, Hend);
    scanp_k<3><<<dim3(BB*NCH*3,2), 256, 0, stream>>>(
        dtb, xc, bc, xz, f_A_log, b_A_log, f_Dp, b_Dp, Aprod, Hend, yb, sidx);
    // ---- fused out-proj + fuse1 (sequential dual-phase reads of permuted yb) ----
    gemm4_k<7,0,3><<<dim3(72,6,1), 256, 0, stream>>>(
        yb, S_YB, DINNER, Ccat, Ccat, 768, 1536,
        h1, 0, nullptr, 0, 768, 0, fuse_b1, fuse_b1, nullptr);
    // ---- fuse2 + residual (staged f32 float4 epilogue) ----
    gemm4_k<0,0,4><<<dim3(72,6,1), 256, 0, stream>>>(
        h1, 0, DINNER, w_2, w_2, 768, 768,
        out, 0, nullptr, 0, 768, 0, fuse_b2, fuse_b2, x);
}